// Round 3
// baseline (306.376 us; speedup 1.0000x reference)
//
#include <hip/hip_runtime.h>
#include <hip/hip_bf16.h>

typedef __hip_bfloat16 bf16;
typedef __bf16 bfv8 __attribute__((ext_vector_type(8)));
typedef float fv4 __attribute__((ext_vector_type(4)));

__device__ __forceinline__ float bf2f(bf16 x){ return __bfloat162float(x); }
__device__ __forceinline__ bf16 f2bf(float x){ return __float2bfloat16(x); }
__device__ __forceinline__ float blo(unsigned u){ return __uint_as_float(u<<16); }
__device__ __forceinline__ float bhi(unsigned u){ return __uint_as_float(u & 0xffff0000u); }
struct __align__(8) bf4v { bf16 x,y,z,w; };
struct __align__(16) bf8s { ushort u[8]; };
__device__ __forceinline__ float4 ldb4(const bf16* p){
  ushort4 u = *(const ushort4*)p;
  float4 r;
  r.x = __uint_as_float(((unsigned)u.x)<<16);
  r.y = __uint_as_float(((unsigned)u.y)<<16);
  r.z = __uint_as_float(((unsigned)u.z)<<16);
  r.w = __uint_as_float(((unsigned)u.w)<<16);
  return r;
}
__device__ __forceinline__ void stb4(bf16* p, float4 v){
  bf4v t; t.x=f2bf(v.x); t.y=f2bf(v.y); t.z=f2bf(v.z); t.w=f2bf(v.w);
  *(bf4v*)p = t;
}

#define L_SEQ 2048
#define DPROJ 2568
#define NCHUNK 16
#define TCH 128

// ---------------- prep: transpose W_in/W_out/W_ydown/W_xup, one dispatch ----------------
__device__ __forceinline__ void tbody(const float* __restrict__ in, bf16* __restrict__ out,
                                      int R, int C, int Cpad, int bx, int by, float (*t)[33])
{
  int c0 = bx*32, r0 = by*32;
  int tx = threadIdx.x & 31, ty = threadIdx.x >> 5;
  for (int i=0;i<32;i+=8){
    int r = r0+i+ty, cc = c0+tx;
    t[i+ty][tx] = (r<R && cc<C) ? in[(size_t)r*C+cc] : 0.f;
  }
  __syncthreads();
  for (int i=0;i<32;i+=8){
    int cc = c0+i+ty, r = r0+tx;
    if (cc<Cpad && r<R) out[(size_t)cc*R + r] = f2bf(t[tx][i+ty]);
  }
}

__global__ void prep(const float* __restrict__ Win, bf16* __restrict__ WinT,
                     const float* __restrict__ Wout, bf16* __restrict__ WoutT,
                     const float* __restrict__ Wyd, bf16* __restrict__ WydT,
                     const float* __restrict__ Wxup, bf16* __restrict__ WxupT)
{
  __shared__ float t[32][33];
  int b = blockIdx.x;
  if (b < 1344){
    tbody(Win, WinT, 512, DPROJ, 2688, b%84, b/84, t);
  } else if (b < 1856){
    int idx = b - 1344;
    tbody(Wout, WoutT, 1024, 512, 512, idx%16, idx/16, t);
  } else if (b < 1864){
    int idx = b - 1856;
    tbody(Wyd, WydT, 128, 64, 64, idx%2, idx/2, t);
  } else {
    int idx = b - 1864;
    tbody(Wxup, WxupT, 64, 128, 128, idx%4, idx/4, t);
  }
}

// ------- GEMM1 (MFMA, 128x128 tile, BK=64): proj = bf16(u) @ W_in + b_in; fp32 side for dt/lam --
__global__ void __launch_bounds__(256) gemm1_mfma(const float* __restrict__ A, const bf16* __restrict__ BT,
                                                  const float* __restrict__ bias, bf16* __restrict__ C,
                                                  float* __restrict__ side)
{
  const int K = 512;
  __shared__ __align__(16) bf16 As[128*72];
  __shared__ __align__(16) bf16 Bs[128*72];
  int tid = threadIdx.x;
  int col0 = blockIdx.x*128, row0 = blockIdx.y*128;
  int wid = tid>>6, lane = tid&63;
  int wm = (wid&1)*64, wn = (wid>>1)*64;
  int lm = lane&15, lq = lane>>4;
  fv4 acc[4][4] = {};
  for (int k0=0;k0<K;k0+=64){
    #pragma unroll
    for (int i=0;i<4;i++){
      int e = tid + i*256;
      int r = e>>3, k8 = (e&7)*8;
      float4 a0 = *(const float4*)&A[(size_t)(row0+r)*K + k0 + k8];
      float4 a1 = *(const float4*)&A[(size_t)(row0+r)*K + k0 + k8 + 4];
      stb4(&As[r*72+k8],   a0);
      stb4(&As[r*72+k8+4], a1);
      *(bf8s*)&Bs[r*72+k8] = *(const bf8s*)&BT[(size_t)(col0+r)*K + k0 + k8];
    }
    __syncthreads();
    #pragma unroll
    for (int ks=0;ks<2;ks++){
      bfv8 af[4], bfr[4];
      #pragma unroll
      for (int mf=0;mf<4;mf++) af[mf] = *(const bfv8*)&As[(wm+mf*16+lm)*72 + ks*32 + lq*8];
      #pragma unroll
      for (int nf=0;nf<4;nf++) bfr[nf] = *(const bfv8*)&Bs[(wn+nf*16+lm)*72 + ks*32 + lq*8];
      #pragma unroll
      for (int mf=0;mf<4;mf++)
        #pragma unroll
        for (int nf=0;nf<4;nf++)
          acc[mf][nf] = __builtin_amdgcn_mfma_f32_16x16x32_bf16(af[mf], bfr[nf], acc[mf][nf], 0,0,0);
    }
    __syncthreads();
  }
  #pragma unroll
  for (int mf=0;mf<4;mf++){
    #pragma unroll
    for (int nf=0;nf<4;nf++){
      int gcol = col0 + wn + nf*16 + lm;
      if (gcol < DPROJ){
        float bia = bias[gcol];
        #pragma unroll
        for (int r=0;r<4;r++){
          int grow = row0 + wm + mf*16 + lq*4 + r;
          float v = acc[mf][nf][r] + bia;
          C[(size_t)grow*DPROJ + gcol] = f2bf(v);
          if (gcol >= 2560) side[grow*8 + (gcol-2560)] = v;
        }
      }
    }
  }
}

// ------- GEMM_OUT (MFMA, BK=128): out(2048x512 fp32) = y2(interleaved ypr bf16) @ W_out --------
__global__ void __launch_bounds__(256) gemmo_mfma(const bf16* __restrict__ Yp, const bf16* __restrict__ BT,
                                                  float* __restrict__ C)
{
  const int K = 1024;
  __shared__ __align__(16) bf16 As[64*136];
  __shared__ __align__(16) bf16 Bs[64*136];
  int tid = threadIdx.x;
  int col0 = blockIdx.x*64, row0 = blockIdx.y*64;
  int wid = tid>>6, lane = tid&63;
  int wm = (wid&1)*32, wn = (wid>>1)*32;
  int lm = lane&15, lq = lane>>4;
  fv4 acc[2][2] = {};
  for (int k0=0;k0<K;k0+=128){
    #pragma unroll
    for (int i=0;i<4;i++){
      int e = tid + i*256;
      int m = e>>4, k8 = (e&15)*8;
      int kg = k0 + k8;
      *(bf8s*)&As[m*136+k8] = *(const bf8s*)&Yp[(size_t)(row0+m)*2048 + ((kg>>6)*128) + 64 + (kg&63)];
      *(bf8s*)&Bs[m*136+k8] = *(const bf8s*)&BT[(size_t)(col0+m)*K + kg];
    }
    __syncthreads();
    #pragma unroll
    for (int ks=0;ks<4;ks++){
      bfv8 af[2], bfr[2];
      #pragma unroll
      for (int mf=0;mf<2;mf++) af[mf] = *(const bfv8*)&As[(wm+mf*16+lm)*136 + ks*32 + lq*8];
      #pragma unroll
      for (int nf=0;nf<2;nf++) bfr[nf] = *(const bfv8*)&Bs[(wn+nf*16+lm)*136 + ks*32 + lq*8];
      #pragma unroll
      for (int mf=0;mf<2;mf++)
        #pragma unroll
        for (int nf=0;nf<2;nf++)
          acc[mf][nf] = __builtin_amdgcn_mfma_f32_16x16x32_bf16(af[mf], bfr[nf], acc[mf][nf], 0,0,0);
    }
    __syncthreads();
  }
  #pragma unroll
  for (int mf=0;mf<2;mf++)
    #pragma unroll
    for (int nf=0;nf<2;nf++){
      int gcol = col0 + wn + nf*16 + lm;
      #pragma unroll
      for (int r=0;r<4;r++){
        int grow = row0 + wm + mf*16 + lq*4 + r;
        C[(size_t)grow*512 + gcol] = acc[mf][nf][r];
      }
    }
}

// ---------------- K23: dt = softplus, lam = sigmoid, csdt = cumsum_l(dt) (single block) ---------
__global__ void k23(const float* __restrict__ dlraw, float* __restrict__ dtb,
                    float* __restrict__ lamb, float* __restrict__ csdt)
{
  __shared__ float raw[L_SEQ*8];
  __shared__ float dts[L_SEQ*4];
  __shared__ float segs[4][64];
  int tid = threadIdx.x;
  for (int e=tid;e<L_SEQ*8;e+=256) raw[e] = dlraw[e];
  __syncthreads();
  int g = tid & 3, seg = tid >> 2;
  for (int i = 0; i < 32; i++){
    int l = seg*32 + i;
    float dr = raw[l*8 + g];
    float lr = raw[l*8 + 4 + g];
    float dt = (dr > 15.f) ? dr : log1pf(__expf(dr));
    dts[l*4+g] = dt;
    dtb[l*4+g] = dt;
    lamb[l*4+g] = 1.f/(1.f+__expf(-lr));
  }
  __syncthreads();
  float s = 0.f;
  for (int i=0;i<32;i++) s += dts[(seg*32+i)*4 + g];
  segs[g][seg] = s;
  __syncthreads();
  if (tid < 4) { float run = 0.f; for (int q=0;q<64;q++){ float t = segs[tid][q]; segs[tid][q] = run; run += t; } }
  __syncthreads();
  float run = segs[g][seg];
  for (int i=0;i<32;i++){ int l = seg*32+i; run += dts[l*4+g]; csdt[l*4+g] = run; }
}

// ------- K45X: fused {x_up MFMA GEMM} + {rmsnorm+RoPE}, block-split --------------------------
__global__ void __launch_bounds__(256) k45x(
  const bf16* __restrict__ proj, const bf16* __restrict__ WxupT, bf16* __restrict__ xup,
  const float* __restrict__ wB, const float* __restrict__ wC,
  const float* __restrict__ biasB, const float* __restrict__ biasC,
  const float* __restrict__ theta_log, const float* __restrict__ csdt,
  bf16* __restrict__ Br, bf16* __restrict__ Cr)
{
  __shared__ __align__(16) bf16 As[128*72];
  __shared__ __align__(16) bf16 Bs[128*72];
  int tid = threadIdx.x;
  if (blockIdx.x < 256){
    // ---- x_up = silu(x).reshape(32768,64) @ W_xup(64,128), one 128x128 tile ----
    int m0 = blockIdx.x*128;
    for (int e = tid; e < 1024; e += 256){
      int n = e>>3, k8 = (e&7)*8;
      *(bf8s*)&Bs[n*72 + k8] = *(const bf8s*)&WxupT[n*64 + k8];
    }
    for (int e = tid; e < 1024; e += 256){
      int r = e>>3, k8 = (e&7)*8;
      int m = m0 + r;
      int l = m >> 4, h = m & 15;
      bf8s v = *(const bf8s*)&proj[(size_t)l*DPROJ + 1024 + h*64 + k8];
      float s[8];
      #pragma unroll
      for (int j=0;j<8;j++){
        float x = blo((unsigned)v.u[j]);
        s[j] = x/(1.f+__expf(-x));
      }
      stb4(&As[r*72 + k8],     make_float4(s[0],s[1],s[2],s[3]));
      stb4(&As[r*72 + k8 + 4], make_float4(s[4],s[5],s[6],s[7]));
    }
    __syncthreads();
    int wid = tid>>6, lane = tid&63;
    int wm = (wid&1)*64, wn = (wid>>1)*64;
    int lm = lane&15, lq = lane>>4;
    fv4 acc[4][4] = {};
    #pragma unroll
    for (int kk=0;kk<64;kk+=32){
      bfv8 af[4], bfr[4];
      #pragma unroll
      for (int mf=0;mf<4;mf++) af[mf] = *(const bfv8*)&As[(wm+mf*16+lm)*72 + kk + lq*8];
      #pragma unroll
      for (int nf=0;nf<4;nf++) bfr[nf] = *(const bfv8*)&Bs[(wn+nf*16+lm)*72 + kk + lq*8];
      #pragma unroll
      for (int mf=0;mf<4;mf++)
        #pragma unroll
        for (int nf=0;nf<4;nf++)
          acc[mf][nf] = __builtin_amdgcn_mfma_f32_16x16x32_bf16(af[mf], bfr[nf], acc[mf][nf], 0,0,0);
    }
    #pragma unroll
    for (int mf=0;mf<4;mf++)
      #pragma unroll
      for (int nf=0;nf<4;nf++){
        int col = wn + nf*16 + lm;
        #pragma unroll
        for (int r=0;r<4;r++){
          int m = m0 + wm + mf*16 + lq*4 + r;
          xup[(size_t)m*128 + col] = f2bf(acc[mf][nf][r]);
        }
      }
  } else {
    // ---- rmsnorm+RoPE for B/C (8 l per block, shuffle-only) ----
    int g = tid >> 6, idx = tid & 63;
    int k = idx >> 2;
    bool is_im = (idx >> 1) & 1;
    float th = __expf(theta_log[g*16+k]);
    float wBv = wB[idx], wCv = wC[idx];
    float bBv = biasB[g*64+idx], bCv = biasC[g*64+idx];
    #pragma unroll
    for (int i=0;i<8;i++){
      int l = (blockIdx.x-256)*8 + i;
      const bf16* pr = proj + (size_t)l*DPROJ;
      float bv = bf2f(pr[2048 + g*64 + idx]);
      float cv = bf2f(pr[2304 + g*64 + idx]);
      float sb = bv*bv, sc = cv*cv;
      #pragma unroll
      for (int off=32; off; off>>=1){ sb += __shfl_xor(sb, off); sc += __shfl_xor(sc, off); }
      float rb = rsqrtf(sb*(1.f/64.f) + 1e-5f);
      float rc = rsqrtf(sc*(1.f/64.f) + 1e-5f);
      float bm = bv*rb*wBv + bBv;
      float cm = cv*rc*wCv + bCv;
      float ang = csdt[l*4+g] * th;
      float ca = cosf(ang), sa = sinf(ang);
      float bp = __shfl_xor(bm, 2);
      float cp = __shfl_xor(cm, 2);
      float bo = is_im ? (bp*sa + bm*ca) : (bm*ca - bp*sa);
      float co = is_im ? (cp*sa + cm*ca) : (cm*ca - cp*sa);
      Br[((size_t)l*4+g)*64 + idx] = f2bf(bo);
      Cr[((size_t)l*4+g)*64 + idx] = f2bf(co);
    }
  }
}

// ------- K6Q (MFMA): y_diag, q-merged — block=(g,c,h4), 512 thr (8 waves: wave w -> q=w>>1,
// rowhalf=w&1). Stages Bs/Xs ONCE per kc (5 balanced iters vs old 2..5 per q-block = 2.8x
// staging cut + perfect CU balance at 256 blocks). Cs staged per-q in prologue -> register
// a-frags; Bsn aliases dead Cs buffer. vT factored out of Fs into the epilogue (row-only).
__global__ void __launch_bounds__(512) k6q(
  const bf16* __restrict__ Br, const bf16* __restrict__ Cr, const bf16* __restrict__ xup,
  const float* __restrict__ dtb, const float* __restrict__ lamb, const float* __restrict__ A_log,
  bf16* __restrict__ ypr, bf16* __restrict__ hfin, float* __restrict__ dcb, float* __restrict__ csb)
{
  __shared__ __align__(16) char arena[63488];
  bf16* CsB  = (bf16*)arena;              // 5120 B: Cs (prologue), then Bsn [32*72] (kc loop)
  bf16* Fs4  = (bf16*)(arena + 5120);     // 4 x [64*72] = 36864 B
  bf16* Bs   = (bf16*)(arena + 41984);    // [64*40] 5120 B
  bf16* Xs   = (bf16*)(arena + 47104);    // [64*72] 9216 B
  float* dt_l = (float*)(arena + 56320);  // [128]
  float* lam_l= (float*)(arena + 56832);  // [128]
  float* cs_l = (float*)(arena + 57344);  // [128]
  float* u1s  = (float*)(arena + 57856);  // [4][160]
  float* u12s = (float*)(arena + 60416);  // [4][160]
  float* vs_  = (float*)(arena + 62976);  // [4][32]
  int g = blockIdx.x, c = blockIdx.y, h4 = blockIdx.z;
  int h = g*4 + h4;
  int tid = threadIdx.x;
  int l0 = c*TCH;
  int w = tid>>6, lane = tid&63, lm = lane&15, lq = lane>>4;
  int qw = w>>1, rh = w&1;
  float Ah = -__expf(A_log[g]);
  float dt_prev = (c>0) ? dtb[(l0-1)*4+g] : 0.f;
  if (tid<128){ dt_l[tid] = dtb[(l0+tid)*4+g]; lam_l[tid] = lamb[(l0+tid)*4+g]; }
  __syncthreads();
  if (tid < 64){
    float a = dt_l[2*tid]*Ah, b = dt_l[2*tid+1]*Ah;
    float s = a + b;
    #pragma unroll
    for (int off=1; off<64; off<<=1){
      float v = __shfl_up(s, off);
      if (tid >= off) s += v;
    }
    cs_l[2*tid+1] = s;
    cs_l[2*tid]   = s - b;
  }
  __syncthreads();
  // per-q coefficient tables
  for (int e = tid; e < 640; e += 512){
    int qq = e/160, jj = e - qq*160;
    float refq = cs_l[qq*32+16];
    float u1v = 0.f, u2v = 0.f;
    if (jj>=1 && jj<=128) u1v = lam_l[jj-1]*dt_l[jj-1]*__expf(fminf(refq-cs_l[jj-1],60.f));
    if (jj<=127){ float dtx = (jj>=1)? dt_l[jj-1] : dt_prev; u2v = (1.f-lam_l[jj])*dtx*__expf(fminf(refq-cs_l[jj],60.f)); }
    u1s[qq*160+jj] = u1v; u12s[qq*160+jj] = u1v+u2v;
  }
  if (tid < 128){ int qq = tid>>5, i = tid&31; vs_[tid] = __expf(fminf(cs_l[qq*32+i]-cs_l[qq*32+16],60.f)); }
  // Cs prologue: stage per-q slice, lift this wave's a-fragments to registers
  bfv8 ca[2];
  for (int qq=0; qq<4; qq++){
    __syncthreads();
    {
      int e4 = tid;
      int tl = e4>>4, c4 = (e4&15)*4;
      bf4v v = *(const bf4v*)&Cr[((size_t)(l0+qq*32+tl)*4+g)*64 + c4];
      bf16 arr[4] = {v.x,v.y,v.z,v.w};
      #pragma unroll
      for (int i=0;i<4;i++){ int q6=c4+i; CsB[((tl<<1)|(q6&1))*40 + (q6>>1)] = arr[i]; }
    }
    __syncthreads();
    if (qw == qq){
      ca[0] = *(const bfv8*)&CsB[(rh*32 +      lm)*40 + lq*8];
      ca[1] = *(const bfv8*)&CsB[(rh*32 + 16 + lm)*40 + lq*8];
    }
  }
  __syncthreads();
  float vfin = __expf(fminf(cs_l[127]-cs_l[112],60.f));
  fv4 acc[2][4] = {};
  fv4 acch[2][2] = {};
  for (int kc=0; kc<5; kc++){
    // stage Bs + Bsn (1 e4/thread)
    {
      int e4 = tid;
      int jjloc = e4>>4, c4 = (e4&15)*4;
      int jj = kc*32 + jjloc; int l = l0-1+jj;
      bf4v v;
      if (l >= 0 && jj <= 128) v = *(const bf4v*)&Br[((size_t)l*4+g)*64 + c4];
      else { v.x=v.y=v.z=v.w = f2bf(0.f); }
      bf16 arr[4] = {v.x,v.y,v.z,v.w};
      #pragma unroll
      for (int i=0;i<4;i++){ int q6=c4+i; Bs[((q6&1)*32+jjloc)*40 + (q6>>1)] = arr[i]; }
      float gcv = vfin * u12s[480+jj];
      #pragma unroll
      for (int i=0;i<4;i++){ int q6=c4+i; CsB[(q6>>1)*72 + (q6&1)*32 + jjloc] = f2bf(gcv*bf2f(arr[i])); }
    }
    // stage Xs (2 e4/thread)
    for (int e4 = tid; e4 < 1024; e4 += 512){
      int jjloc = e4>>5, c4 = (e4&31)*4;
      int jj = kc*32+jjloc; int l = l0-1+jj;
      bf4v v;
      if (l>=0 && jj<=128) v = *(const bf4v*)&xup[((size_t)l*16 + h)*128 + c4];
      else { v.x=v.y=v.z=v.w = f2bf(0.f); }
      bf16 arr[4] = {v.x,v.y,v.z,v.w};
      #pragma unroll
      for (int i=0;i<4;i++){ int q7=c4+i; Xs[(q7>>1)*72 + (q7&1)*32 + jjloc] = arr[i]; }
    }
    __syncthreads();
    // CB MFMA + Fs (waves with kc < qw+2)
    if (kc < qw+2){
      bf16* Fq = Fs4 + qw*4608;
      fv4 zz = {0.f,0.f,0.f,0.f};
      #pragma unroll
      for (int mt=0;mt<2;mt++){
        int rb = rh*32 + mt*16 + lq*4;
        #pragma unroll
        for (int nt=0;nt<4;nt++){
          bfv8 b = *(const bfv8*)&Bs[(nt*16+lm)*40 + lq*8];
          fv4 s = __builtin_amdgcn_mfma_f32_16x16x32_bf16(ca[mt], b, zz, 0,0,0);
          int col = nt*16+lm;
          int jj = kc*32 + (col&31);
          float u1v = u1s[qw*160+jj], u12v = u12s[qw*160+jj];
          #pragma unroll
          for (int r=0;r<4;r++){
            int row = rb + r;
            float cf;
            if (kc < qw) cf = u12v;
            else {
              int T = qw*32 + (row>>1);
              if (kc == qw) cf = (jj<=T) ? u12v : ((jj==T+1) ? u1v : 0.f);
              else          cf = (jj==T+1) ? u1v : 0.f;
            }
            Fq[row*72+col] = f2bf(cf*s[r]);
          }
        }
      }
    }
    __syncthreads();
    // FX MFMA (waves with kc < qw+2)
    if (kc < qw+2){
      bf16* Fq = Fs4 + qw*4608;
      #pragma unroll
      for (int mt=0;mt<2;mt++)
        #pragma unroll
        for (int r2=0;r2<2;r2++){
          bfv8 a = *(const bfv8*)&Fq[(rh*32+mt*16+lm)*72 + r2*32 + lq*8];
          #pragma unroll
          for (int nt=0;nt<4;nt++){
            bfv8 b = *(const bfv8*)&Xs[(nt*16+lm)*72 + r2*32 + lq*8];
            acc[mt][nt] = __builtin_amdgcn_mfma_f32_16x16x32_bf16(a, b, acc[mt][nt], 0,0,0);
          }
        }
    }
    // h_final accumulation (q==3 waves, every kc)
    if (qw == 3){
      #pragma unroll
      for (int mt=0;mt<2;mt++)
        #pragma unroll
        for (int r2=0;r2<2;r2++){
          bfv8 a = *(const bfv8*)&Xs[(rh*32+mt*16+lm)*72 + r2*32 + lq*8];
          #pragma unroll
          for (int nt2=0;nt2<2;nt2++){
            bfv8 b = *(const bfv8*)&CsB[(nt2*16+lm)*72 + r2*32 + lq*8];
            acch[mt][nt2] = __builtin_amdgcn_mfma_f32_16x16x32_bf16(a, b, acch[mt][nt2], 0,0,0);
          }
        }
    }
    __syncthreads();
  }
  // epilogue: vT scaling (factored out of Fs) + ypr store
  #pragma unroll
  for (int mt=0;mt<2;mt++)
    #pragma unroll
    for (int nt=0;nt<4;nt++){
      int p = nt*16+lm;
      #pragma unroll
      for (int r=0;r<4;r++){
        int row = rh*32 + mt*16 + lq*4 + r;
        int T = qw*32 + (row>>1), r1 = row&1;
        float vT = vs_[qw*32 + (row>>1)];
        ypr[((size_t)(l0+T)*16 + h)*128 + p*2+r1] = f2bf(acc[mt][nt][r]*vT);
      }
    }
  if (qw == 3){
    #pragma unroll
    for (int mt=0;mt<2;mt++)
      #pragma unroll
      for (int nt2=0;nt2<2;nt2++){
        int n = nt2*16+lm;
        #pragma unroll
        for (int r=0;r<4;r++){
          int p = rh*32 + mt*16 + lq*4 + r;
          hfin[(((size_t)c*16+h)*64 + p)*32 + n] = f2bf(acch[mt][nt2][r]);
        }
      }
  }
  if (tid == 0) dcb[c*16+h] = __expf(cs_l[127]);
  if (h4 == 0 && tid < 128) csb[(c*4+g)*128 + tid] = cs_l[tid];
}

// ------- K8AF: fused inter-chunk scan + y_off (MFMA) + ydown (MFMA) + gates, per (c,h) ---------
__global__ void __launch_bounds__(256) k8af(
  const bf16* __restrict__ Cr, const bf16* __restrict__ hfin,
  const float* __restrict__ dcb, const float* __restrict__ csb,
  bf16* __restrict__ ypr, const bf16* __restrict__ WydT,
  const bf16* __restrict__ proj, const float* __restrict__ Dp)
{
  __shared__ __align__(16) char arena[52224];
  bf16* C2s = (bf16*)arena;              // [256*40] 20480 B (phase 1)
  bf16* hT  = (bf16*)(arena + 20480);    // [64*40]   5120 B (phase 1)
  float* cse = (float*)(arena + 25600);  // [128]      512 B (phase 1)
  bf16* Yf  = (bf16*)arena;              // [128*136] 34816 B (phase 2, aliases C2s/hT/cse)
  bf16* Wds = (bf16*)(arena + 34816);    // [64*136] 17408 B (both phases)
  int h = blockIdx.x, c = blockIdx.y;
  int g = h >> 2;
  int tid = threadIdx.x;
  int l0 = c*TCH;
  int w = tid>>6, lane = tid&63, lm = lane&15, lq = lane>>4;
  for (int e4 = tid; e4 < 2048; e4 += 256){
    int tl = e4>>4, c4 = (e4&15)*4;
    bf4v v = *(const bf4v*)&Cr[((size_t)(l0+tl)*4+g)*64 + c4];
    bf16 arr[4] = {v.x,v.y,v.z,v.w};
    #pragma unroll
    for (int i=0;i<4;i++){ int q6=c4+i; C2s[((tl<<1)|(q6&1))*40 + (q6>>1)] = arr[i]; }
  }
  for (int e = tid; e < 1024; e += 256){
    int qq = e>>4, k8 = (e&15)*8;
    *(bf8s*)&Wds[qq*136 + k8] = *(const bf8s*)&WydT[qq*128 + k8];
  }
  {
    int e0 = tid*8;
    float carry[8] = {};
    for (int j = 0; j < c; j++){
      float dc = dcb[j*16+h];
      float4 a = ldb4(&hfin[((size_t)j*16+h)*2048 + e0]);
      float4 b = ldb4(&hfin[((size_t)j*16+h)*2048 + e0 + 4]);
      carry[0]=carry[0]*dc+a.x; carry[1]=carry[1]*dc+a.y; carry[2]=carry[2]*dc+a.z; carry[3]=carry[3]*dc+a.w;
      carry[4]=carry[4]*dc+b.x; carry[5]=carry[5]*dc+b.y; carry[6]=carry[6]*dc+b.z; carry[7]=carry[7]*dc+b.w;
    }
    int p = e0>>5, n = e0&31;
    stb4(&hT[p*40+n],   make_float4(carry[0],carry[1],carry[2],carry[3]));
    stb4(&hT[p*40+n+4], make_float4(carry[4],carry[5],carry[6],carry[7]));
  }
  if (tid < 128) cse[tid] = __expf(csb[(c*4+g)*128 + tid]);
  __syncthreads();
  float yfull[4][4][4];
  fv4 zz = {0.f,0.f,0.f,0.f};
  #pragma unroll
  for (int mi=0;mi<4;mi++){
    int mt = w*4 + mi;
    bfv8 a = *(const bfv8*)&C2s[(mt*16+lm)*40 + lq*8];
    #pragma unroll
    for (int nt=0;nt<4;nt++){
      bfv8 b = *(const bfv8*)&hT[(nt*16+lm)*40 + lq*8];
      fv4 s = __builtin_amdgcn_mfma_f32_16x16x32_bf16(a, b, zz, 0,0,0);
      int p = nt*16+lm;
      #pragma unroll
      for (int r=0;r<4;r++){
        int row = mt*16+lq*4+r;
        int tl = row>>1, r1 = row&1;
        float yd = bf2f(ypr[((size_t)(l0+tl)*16 + h)*128 + p*2 + r1]);
        yfull[mi][nt][r] = yd + cse[tl]*s[r];
      }
    }
  }
  __syncthreads();
  #pragma unroll
  for (int mi=0;mi<4;mi++){
    int mt = w*4 + mi;
    #pragma unroll
    for (int nt=0;nt<4;nt++){
      int p = nt*16+lm;
      #pragma unroll
      for (int r=0;r<4;r++){
        int row = mt*16+lq*4+r;
        int tl = row>>1, r1 = row&1;
        Yf[tl*136 + p*2 + r1] = f2bf(yfull[mi][nt][r]);
      }
    }
  }
  __syncthreads();
  fv4 acc2[2][4] = {};
  #pragma unroll
  for (int kq=0;kq<4;kq++){
    #pragma unroll
    for (int m2=0;m2<2;m2++){
      bfv8 a = *(const bfv8*)&Yf[((w*2+m2)*16+lm)*136 + kq*32 + lq*8];
      #pragma unroll
      for (int nt2=0;nt2<4;nt2++){
        bfv8 b = *(const bfv8*)&Wds[(nt2*16+lm)*136 + kq*32 + lq*8];
        acc2[m2][nt2] = __builtin_amdgcn_mfma_f32_16x16x32_bf16(a, b, acc2[m2][nt2], 0,0,0);
      }
    }
  }
  float dv = Dp[h];
  #pragma unroll
  for (int m2=0;m2<2;m2++){
    #pragma unroll
    for (int nt2=0;nt2<4;nt2++){
      int qq = nt2*16+lm;
      #pragma unroll
      for (int r=0;r<4;r++){
        int tl = (w*2+m2)*16 + lq*4 + r;
        size_t lrow = (size_t)(l0+tl)*DPROJ;
        float x = bf2f(proj[lrow + 1024 + h*64 + qq]);
        float z = bf2f(proj[lrow + h*64 + qq]);
        float xs = x/(1.f+__expf(-x));
        float zs = z/(1.f+__expf(-z));
        float outv = (acc2[m2][nt2][r] + dv*xs)*zs;
        ypr[((size_t)(l0+tl)*16 + h)*128 + 64 + qq] = f2bf(outv);
      }
    }
  }
}

extern "C" void kernel_launch(void* const* d_in, const int* in_sizes, int n_in,
                              void* d_out, int out_size, void* d_ws, size_t ws_size,
                              hipStream_t stream) {
  const float* u       = (const float*)d_in[0];
  const float* W_in    = (const float*)d_in[1];
  const float* b_in    = (const float*)d_in[2];
  const float* W_xup   = (const float*)d_in[3];
  const float* W_ydown = (const float*)d_in[4];
  const float* A_log   = (const float*)d_in[5];
  const float* theta_l = (const float*)d_in[6];
  const float* D_p     = (const float*)d_in[7];
  const float* wB      = (const float*)d_in[8];
  const float* wC      = (const float*)d_in[9];
  const float* biasB   = (const float*)d_in[10];
  const float* biasC   = (const float*)d_in[11];
  const float* W_out   = (const float*)d_in[12];
  float* out = (float*)d_out;

  char* w = (char*)d_ws;
  bf16*  proj  = (bf16*)(w);                       // 10,518,528 B
  float* dlraw = (float*)(w + 10518528);           //     65,536 B
  float* dtb   = (float*)(w + 10584064);           //     32,768 B
  float* lamb  = (float*)(w + 10616832);           //     32,768 B
  float* csdt  = (float*)(w + 10649600);           //     32,768 B
  bf16*  Brb   = (bf16*)(w + 10682368);            //  1,048,576 B
  bf16*  Crb   = (bf16*)(w + 11730944);            //  1,048,576 B
  bf16*  xupb  = (bf16*)(w + 12779520);            //  8,388,608 B
  bf16*  hfin  = (bf16*)(w + 21168128);            //  1,048,576 B
  bf16*  WxupT = (bf16*)(w + 22216704);            //     16,384 B (slack after hfin)
  float* dcb   = (float*)(w + 23265280);           //      1,024 B
  float* csb   = (float*)(w + 23266304);           //     32,768 B
  bf16*  ypr   = (bf16*)(w + 23299072);            //  8,388,608 B
  bf16*  WinT  = (bf16*)(w + 23299072);            //  aliased over ypr (dead once k6q writes ypr)
  bf16*  WoutT = (bf16*)(w + 33784832);            //  1,048,576 B
  bf16*  WydT  = (bf16*)(w + 34833408);            //     16,384 B

  prep<<<1872,256,0,stream>>>(W_in, WinT, W_out, WoutT, W_ydown, WydT, W_xup, WxupT);
  gemm1_mfma<<<dim3(21,16),256,0,stream>>>(u, WinT, b_in, proj, dlraw);
  k23<<<1,256,0,stream>>>(dlraw, dtb, lamb, csdt);
  k45x<<<512,256,0,stream>>>(proj, WxupT, xupb, wB, wC, biasB, biasC, theta_l, csdt, Brb, Crb);
  k6q<<<dim3(4,16,4),512,0,stream>>>(Brb, Crb, xupb, dtb, lamb, A_log, ypr, hfin, dcb, csb);
  k8af<<<dim3(16,16),256,0,stream>>>(Crb, hfin, dcb, csb, ypr, WydT, proj, D_p);
  gemmo_mfma<<<dim3(8,32),256,0,stream>>>(ypr, WoutT, out);
}

// Round 4
// 177.750 us; speedup vs baseline: 1.7236x; 1.7236x over previous
//
#include <hip/hip_runtime.h>
#include <hip/hip_bf16.h>

typedef __hip_bfloat16 bf16;
typedef __bf16 bfv8 __attribute__((ext_vector_type(8)));
typedef float fv4 __attribute__((ext_vector_type(4)));

__device__ __forceinline__ float bf2f(bf16 x){ return __bfloat162float(x); }
__device__ __forceinline__ bf16 f2bf(float x){ return __float2bfloat16(x); }
__device__ __forceinline__ float blo(unsigned u){ return __uint_as_float(u<<16); }
__device__ __forceinline__ float bhi(unsigned u){ return __uint_as_float(u & 0xffff0000u); }
struct __align__(8) bf4v { bf16 x,y,z,w; };
struct __align__(16) bf8s { ushort u[8]; };
__device__ __forceinline__ float4 ldb4(const bf16* p){
  ushort4 u = *(const ushort4*)p;
  float4 r;
  r.x = __uint_as_float(((unsigned)u.x)<<16);
  r.y = __uint_as_float(((unsigned)u.y)<<16);
  r.z = __uint_as_float(((unsigned)u.z)<<16);
  r.w = __uint_as_float(((unsigned)u.w)<<16);
  return r;
}
__device__ __forceinline__ void stb4(bf16* p, float4 v){
  bf4v t; t.x=f2bf(v.x); t.y=f2bf(v.y); t.z=f2bf(v.z); t.w=f2bf(v.w);
  *(bf4v*)p = t;
}

#define L_SEQ 2048
#define DPROJ 2568
#define NCHUNK 16
#define TCH 128

// ---------------- prep: transpose W_in/W_out/W_ydown/W_xup, one dispatch ----------------
__device__ __forceinline__ void tbody(const float* __restrict__ in, bf16* __restrict__ out,
                                      int R, int C, int Cpad, int bx, int by, float (*t)[33])
{
  int c0 = bx*32, r0 = by*32;
  int tx = threadIdx.x & 31, ty = threadIdx.x >> 5;
  for (int i=0;i<32;i+=8){
    int r = r0+i+ty, cc = c0+tx;
    t[i+ty][tx] = (r<R && cc<C) ? in[(size_t)r*C+cc] : 0.f;
  }
  __syncthreads();
  for (int i=0;i<32;i+=8){
    int cc = c0+i+ty, r = r0+tx;
    if (cc<Cpad && r<R) out[(size_t)cc*R + r] = f2bf(t[tx][i+ty]);
  }
}

__global__ void prep(const float* __restrict__ Win, bf16* __restrict__ WinT,
                     const float* __restrict__ Wout, bf16* __restrict__ WoutT,
                     const float* __restrict__ Wyd, bf16* __restrict__ WydT,
                     const float* __restrict__ Wxup, bf16* __restrict__ WxupT)
{
  __shared__ float t[32][33];
  int b = blockIdx.x;
  if (b < 1344){
    tbody(Win, WinT, 512, DPROJ, 2688, b%84, b/84, t);
  } else if (b < 1856){
    int idx = b - 1344;
    tbody(Wout, WoutT, 1024, 512, 512, idx%16, idx/16, t);
  } else if (b < 1864){
    int idx = b - 1856;
    tbody(Wyd, WydT, 128, 64, 64, idx%2, idx/2, t);
  } else {
    int idx = b - 1864;
    tbody(Wxup, WxupT, 64, 128, 128, idx%4, idx/4, t);
  }
}

// ------- GEMM1 (MFMA, 128x128 tile, BK=64): proj = bf16(u) @ W_in + b_in; fp32 side for dt/lam --
__global__ void __launch_bounds__(256) gemm1_mfma(const float* __restrict__ A, const bf16* __restrict__ BT,
                                                  const float* __restrict__ bias, bf16* __restrict__ C,
                                                  float* __restrict__ side)
{
  const int K = 512;
  __shared__ __align__(16) bf16 As[128*72];
  __shared__ __align__(16) bf16 Bs[128*72];
  int tid = threadIdx.x;
  int col0 = blockIdx.x*128, row0 = blockIdx.y*128;
  int wid = tid>>6, lane = tid&63;
  int wm = (wid&1)*64, wn = (wid>>1)*64;
  int lm = lane&15, lq = lane>>4;
  fv4 acc[4][4] = {};
  for (int k0=0;k0<K;k0+=64){
    #pragma unroll
    for (int i=0;i<4;i++){
      int e = tid + i*256;
      int r = e>>3, k8 = (e&7)*8;
      float4 a0 = *(const float4*)&A[(size_t)(row0+r)*K + k0 + k8];
      float4 a1 = *(const float4*)&A[(size_t)(row0+r)*K + k0 + k8 + 4];
      stb4(&As[r*72+k8],   a0);
      stb4(&As[r*72+k8+4], a1);
      *(bf8s*)&Bs[r*72+k8] = *(const bf8s*)&BT[(size_t)(col0+r)*K + k0 + k8];
    }
    __syncthreads();
    #pragma unroll
    for (int ks=0;ks<2;ks++){
      bfv8 af[4], bfr[4];
      #pragma unroll
      for (int mf=0;mf<4;mf++) af[mf] = *(const bfv8*)&As[(wm+mf*16+lm)*72 + ks*32 + lq*8];
      #pragma unroll
      for (int nf=0;nf<4;nf++) bfr[nf] = *(const bfv8*)&Bs[(wn+nf*16+lm)*72 + ks*32 + lq*8];
      #pragma unroll
      for (int mf=0;mf<4;mf++)
        #pragma unroll
        for (int nf=0;nf<4;nf++)
          acc[mf][nf] = __builtin_amdgcn_mfma_f32_16x16x32_bf16(af[mf], bfr[nf], acc[mf][nf], 0,0,0);
    }
    __syncthreads();
  }
  #pragma unroll
  for (int mf=0;mf<4;mf++){
    #pragma unroll
    for (int nf=0;nf<4;nf++){
      int gcol = col0 + wn + nf*16 + lm;
      if (gcol < DPROJ){
        float bia = bias[gcol];
        #pragma unroll
        for (int r=0;r<4;r++){
          int grow = row0 + wm + mf*16 + lq*4 + r;
          float v = acc[mf][nf][r] + bia;
          C[(size_t)grow*DPROJ + gcol] = f2bf(v);
          if (gcol >= 2560) side[grow*8 + (gcol-2560)] = v;
        }
      }
    }
  }
}

// ------- GEMM_OUT (MFMA, BK=128): out(2048x512 fp32) = y2(interleaved ypr bf16) @ W_out --------
__global__ void __launch_bounds__(256) gemmo_mfma(const bf16* __restrict__ Yp, const bf16* __restrict__ BT,
                                                  float* __restrict__ C)
{
  const int K = 1024;
  __shared__ __align__(16) bf16 As[64*136];
  __shared__ __align__(16) bf16 Bs[64*136];
  int tid = threadIdx.x;
  int col0 = blockIdx.x*64, row0 = blockIdx.y*64;
  int wid = tid>>6, lane = tid&63;
  int wm = (wid&1)*32, wn = (wid>>1)*32;
  int lm = lane&15, lq = lane>>4;
  fv4 acc[2][2] = {};
  for (int k0=0;k0<K;k0+=128){
    #pragma unroll
    for (int i=0;i<4;i++){
      int e = tid + i*256;
      int m = e>>4, k8 = (e&15)*8;
      int kg = k0 + k8;
      *(bf8s*)&As[m*136+k8] = *(const bf8s*)&Yp[(size_t)(row0+m)*2048 + ((kg>>6)*128) + 64 + (kg&63)];
      *(bf8s*)&Bs[m*136+k8] = *(const bf8s*)&BT[(size_t)(col0+m)*K + kg];
    }
    __syncthreads();
    #pragma unroll
    for (int ks=0;ks<4;ks++){
      bfv8 af[2], bfr[2];
      #pragma unroll
      for (int mf=0;mf<2;mf++) af[mf] = *(const bfv8*)&As[(wm+mf*16+lm)*136 + ks*32 + lq*8];
      #pragma unroll
      for (int nf=0;nf<2;nf++) bfr[nf] = *(const bfv8*)&Bs[(wn+nf*16+lm)*136 + ks*32 + lq*8];
      #pragma unroll
      for (int mf=0;mf<2;mf++)
        #pragma unroll
        for (int nf=0;nf<2;nf++)
          acc[mf][nf] = __builtin_amdgcn_mfma_f32_16x16x32_bf16(af[mf], bfr[nf], acc[mf][nf], 0,0,0);
    }
    __syncthreads();
  }
  #pragma unroll
  for (int mf=0;mf<2;mf++)
    #pragma unroll
    for (int nf=0;nf<2;nf++){
      int gcol = col0 + wn + nf*16 + lm;
      #pragma unroll
      for (int r=0;r<4;r++){
        int grow = row0 + wm + mf*16 + lq*4 + r;
        C[(size_t)grow*512 + gcol] = acc[mf][nf][r];
      }
    }
}

// ---- K23: dt=softplus, lam=sigmoid, csdt=cumsum_l(dt). 1024 thr, 3-level parallel scan. ----
// Old version: 256 thr, serial 32-iter loops + serial 64-seg scan on ONE CU (~89us measured).
// New: thread=(g, 8-l segment); per-g wave shfl_up scan (stride-4); 16x4 wave totals scanned
// by one wave; 2 barriers total.
__global__ void __launch_bounds__(1024) k23(const float* __restrict__ dlraw, float* __restrict__ dtb,
                    float* __restrict__ lamb, float* __restrict__ csdt)
{
  __shared__ float wt[16][4];
  __shared__ float wo[16][4];
  int tid = threadIdx.x;
  int g = tid & 3, seg = tid >> 2;       // seg 0..255, 8 l each
  int lane = tid & 63, wave = tid >> 6;  // 16 waves
  float dt[8];
  float lsum = 0.f;
  #pragma unroll
  for (int i=0;i<8;i++){
    int l = seg*8 + i;
    float dr = dlraw[l*8 + g];
    float lr = dlraw[l*8 + 4 + g];
    float d = (dr > 15.f) ? dr : log1pf(__expf(dr));
    dt[i] = d;
    lsum += d;
    dtb[l*4+g] = d;
    lamb[l*4+g] = 1.f/(1.f+__expf(-lr));
  }
  // per-g inclusive scan across the wave (lanes stride 4 share g)
  float s = lsum;
  #pragma unroll
  for (int off=4; off<64; off<<=1){
    float v = __shfl_up(s, off);
    if (lane >= off) s += v;
  }
  if (lane >= 60) wt[wave][g] = s;       // lanes 60..63: per-(wave,g) totals
  __syncthreads();
  if (tid < 64){
    int w2 = tid >> 2, g2 = tid & 3;
    float r = 0.f;
    for (int j=0;j<w2;j++) r += wt[j][g2];
    wo[w2][g2] = r;
  }
  __syncthreads();
  float run = wo[wave][g] + (s - lsum);  // global exclusive prefix for this thread's 8 l
  #pragma unroll
  for (int i=0;i<8;i++){
    int l = seg*8 + i;
    run += dt[i];
    csdt[l*4+g] = run;
  }
}

// ------- K45X: fused {x_up MFMA GEMM} + {rmsnorm+RoPE}, block-split --------------------------
__global__ void __launch_bounds__(256) k45x(
  const bf16* __restrict__ proj, const bf16* __restrict__ WxupT, bf16* __restrict__ xup,
  const float* __restrict__ wB, const float* __restrict__ wC,
  const float* __restrict__ biasB, const float* __restrict__ biasC,
  const float* __restrict__ theta_log, const float* __restrict__ csdt,
  bf16* __restrict__ Br, bf16* __restrict__ Cr)
{
  __shared__ __align__(16) bf16 As[128*72];
  __shared__ __align__(16) bf16 Bs[128*72];
  int tid = threadIdx.x;
  if (blockIdx.x < 256){
    // ---- x_up = silu(x).reshape(32768,64) @ W_xup(64,128), one 128x128 tile ----
    int m0 = blockIdx.x*128;
    for (int e = tid; e < 1024; e += 256){
      int n = e>>3, k8 = (e&7)*8;
      *(bf8s*)&Bs[n*72 + k8] = *(const bf8s*)&WxupT[n*64 + k8];
    }
    for (int e = tid; e < 1024; e += 256){
      int r = e>>3, k8 = (e&7)*8;
      int m = m0 + r;
      int l = m >> 4, h = m & 15;
      bf8s v = *(const bf8s*)&proj[(size_t)l*DPROJ + 1024 + h*64 + k8];
      float s[8];
      #pragma unroll
      for (int j=0;j<8;j++){
        float x = blo((unsigned)v.u[j]);
        s[j] = x/(1.f+__expf(-x));
      }
      stb4(&As[r*72 + k8],     make_float4(s[0],s[1],s[2],s[3]));
      stb4(&As[r*72 + k8 + 4], make_float4(s[4],s[5],s[6],s[7]));
    }
    __syncthreads();
    int wid = tid>>6, lane = tid&63;
    int wm = (wid&1)*64, wn = (wid>>1)*64;
    int lm = lane&15, lq = lane>>4;
    fv4 acc[4][4] = {};
    #pragma unroll
    for (int kk=0;kk<64;kk+=32){
      bfv8 af[4], bfr[4];
      #pragma unroll
      for (int mf=0;mf<4;mf++) af[mf] = *(const bfv8*)&As[(wm+mf*16+lm)*72 + kk + lq*8];
      #pragma unroll
      for (int nf=0;nf<4;nf++) bfr[nf] = *(const bfv8*)&Bs[(wn+nf*16+lm)*72 + kk + lq*8];
      #pragma unroll
      for (int mf=0;mf<4;mf++)
        #pragma unroll
        for (int nf=0;nf<4;nf++)
          acc[mf][nf] = __builtin_amdgcn_mfma_f32_16x16x32_bf16(af[mf], bfr[nf], acc[mf][nf], 0,0,0);
    }
    #pragma unroll
    for (int mf=0;mf<4;mf++)
      #pragma unroll
      for (int nf=0;nf<4;nf++){
        int col = wn + nf*16 + lm;
        #pragma unroll
        for (int r=0;r<4;r++){
          int m = m0 + wm + mf*16 + lq*4 + r;
          xup[(size_t)m*128 + col] = f2bf(acc[mf][nf][r]);
        }
      }
  } else {
    // ---- rmsnorm+RoPE for B/C (8 l per block, shuffle-only) ----
    int g = tid >> 6, idx = tid & 63;
    int k = idx >> 2;
    bool is_im = (idx >> 1) & 1;
    float th = __expf(theta_log[g*16+k]);
    float wBv = wB[idx], wCv = wC[idx];
    float bBv = biasB[g*64+idx], bCv = biasC[g*64+idx];
    #pragma unroll
    for (int i=0;i<8;i++){
      int l = (blockIdx.x-256)*8 + i;
      const bf16* pr = proj + (size_t)l*DPROJ;
      float bv = bf2f(pr[2048 + g*64 + idx]);
      float cv = bf2f(pr[2304 + g*64 + idx]);
      float sb = bv*bv, sc = cv*cv;
      #pragma unroll
      for (int off=32; off; off>>=1){ sb += __shfl_xor(sb, off); sc += __shfl_xor(sc, off); }
      float rb = rsqrtf(sb*(1.f/64.f) + 1e-5f);
      float rc = rsqrtf(sc*(1.f/64.f) + 1e-5f);
      float bm = bv*rb*wBv + bBv;
      float cm = cv*rc*wCv + bCv;
      float ang = csdt[l*4+g] * th;
      float ca = cosf(ang), sa = sinf(ang);
      float bp = __shfl_xor(bm, 2);
      float cp = __shfl_xor(cm, 2);
      float bo = is_im ? (bp*sa + bm*ca) : (bm*ca - bp*sa);
      float co = is_im ? (cp*sa + cm*ca) : (cm*ca - cp*sa);
      Br[((size_t)l*4+g)*64 + idx] = f2bf(bo);
      Cr[((size_t)l*4+g)*64 + idx] = f2bf(co);
    }
  }
}

// ------- K6Y (MFMA): y_diag per (chunk, group, t-quarter, head); q==3 also emits h_final --------
// F-coef factorization: coef(T,jj) = v[T]*(u1[jj]*[jj<=T+1] + u2[jj]*[jj<=T]), v/u precomputed
// in-block (hidden by 1024-block occupancy — R12/R13 showed hoisting this regresses).
// Prologue scan: single-wave shfl_up (2 barriers) instead of 128-wide Hillis-Steele (14 barriers).
// NOTE R3: q-merged variant (1 block/CU, 512 thr) regressed 191->306us — occupancy-backed
// inter-block overlap beats staging dedup here. Keep 4 blocks/CU structure.
__global__ void __launch_bounds__(256) k6y(
  const bf16* __restrict__ Br, const bf16* __restrict__ Cr, const bf16* __restrict__ xup,
  const float* __restrict__ dtb, const float* __restrict__ lamb, const float* __restrict__ A_log,
  bf16* __restrict__ ypr, bf16* __restrict__ hfin, float* __restrict__ dcb, float* __restrict__ csb)
{
  __shared__ __align__(16) bf16 Cs[64*40];
  __shared__ __align__(16) bf16 Bs[64*40];
  __shared__ __align__(16) bf16 Bsn[32*72];
  __shared__ __align__(16) bf16 Fs[64*72];
  __shared__ __align__(16) bf16 Xs[64*72];
  __shared__ float dt_l[128], lam_l[128], cs_l[128];
  __shared__ float u1s[160], u12s[160], vs_[32];
  int bx = blockIdx.x; int g = bx & 3, q = bx >> 2;
  int c = blockIdx.y;
  int h4 = blockIdx.z;
  int h = g*4 + h4;
  int tid = threadIdx.x;
  int l0 = c*TCH;
  int w = tid>>6, lane = tid&63, lm = lane&15, lq = lane>>4;
  float Ah = -__expf(A_log[g]);
  float dt_prev = (c>0) ? dtb[(l0-1)*4+g] : 0.f;
  if (tid<128){ dt_l[tid] = dtb[(l0+tid)*4+g]; lam_l[tid] = lamb[(l0+tid)*4+g]; }
  __syncthreads();
  if (tid < 64){
    float a = dt_l[2*tid]*Ah, b = dt_l[2*tid+1]*Ah;
    float s = a + b;
    #pragma unroll
    for (int off=1; off<64; off<<=1){
      float v = __shfl_up(s, off);
      if (tid >= off) s += v;
    }
    cs_l[2*tid+1] = s;
    cs_l[2*tid]   = s - b;
  }
  __syncthreads();
  float ref = cs_l[q*32+16];
  if (tid < 160){
    int jj = tid;
    float u1v = 0.f, u2v = 0.f;
    if (jj>=1 && jj<=128) u1v = lam_l[jj-1]*dt_l[jj-1]*__expf(fminf(ref-cs_l[jj-1],60.f));
    if (jj<=127){ float dtx = (jj>=1)? dt_l[jj-1] : dt_prev; u2v = (1.f-lam_l[jj])*dtx*__expf(fminf(ref-cs_l[jj],60.f)); }
    u1s[jj] = u1v; u12s[jj] = u1v+u2v;
  }
  if (tid < 32) vs_[tid] = __expf(fminf(cs_l[q*32+tid]-ref,60.f));
  for (int e4 = tid; e4 < 512; e4 += 256){
    int tl = e4>>4, c4 = (e4&15)*4;
    bf4v v = *(const bf4v*)&Cr[((size_t)(l0+q*32+tl)*4+g)*64 + c4];
    bf16 arr[4] = {v.x,v.y,v.z,v.w};
    #pragma unroll
    for (int i=0;i<4;i++){ int q6=c4+i; Cs[((tl<<1)|(q6&1))*40 + (q6>>1)] = arr[i]; }
  }
  __syncthreads();   // covers u1s/u12s/vs_ and Cs before use
  float vfin = __expf(fminf(cs_l[127]-ref,60.f));
  fv4 acc[4] = {};
  fv4 acch[2] = {};
  int nch = (q+2 < 5) ? (q+2) : 5;
  for (int kc=0; kc<nch; kc++){
    for (int e4 = tid; e4 < 512; e4 += 256){
      int jjloc = e4>>4, c4 = (e4&15)*4;
      int jj = kc*32 + jjloc; int l = l0-1+jj;
      bf4v v;
      if (l >= 0 && jj <= 128) v = *(const bf4v*)&Br[((size_t)l*4+g)*64 + c4];
      else { v.x=v.y=v.z=v.w = f2bf(0.f); }
      bf16 arr[4] = {v.x,v.y,v.z,v.w};
      #pragma unroll
      for (int i=0;i<4;i++){ int q6=c4+i; Bs[((q6&1)*32+jjloc)*40 + (q6>>1)] = arr[i]; }
      if (q == 3){
        float gcv = vfin * u12s[jj];
        #pragma unroll
        for (int i=0;i<4;i++){ int q6=c4+i; Bsn[(q6>>1)*72 + (q6&1)*32 + jjloc] = f2bf(gcv*bf2f(arr[i])); }
      }
    }
    for (int e4 = tid; e4 < 1024; e4 += 256){
      int jjloc = e4>>5, c4 = (e4&31)*4;
      int jj = kc*32+jjloc; int l = l0-1+jj;
      bf4v v;
      if (l>=0 && jj<=128) v = *(const bf4v*)&xup[((size_t)l*16 + h)*128 + c4];
      else { v.x=v.y=v.z=v.w = f2bf(0.f); }
      bf16 arr[4] = {v.x,v.y,v.z,v.w};
      #pragma unroll
      for (int i=0;i<4;i++){ int q7=c4+i; Xs[(q7>>1)*72 + (q7&1)*32 + jjloc] = arr[i]; }
    }
    __syncthreads();
    {
      bfv8 a = *(const bfv8*)&Cs[(w*16+lm)*40 + lq*8];
      fv4 zz = {0.f,0.f,0.f,0.f};
      int rb = w*16 + lq*4;
      float vA = vs_[rb>>1];
      float vB = vs_[(rb>>1)+1];
      #pragma unroll
      for (int nt=0;nt<4;nt++){
        bfv8 b = *(const bfv8*)&Bs[(nt*16+lm)*40 + lq*8];
        fv4 s = __builtin_amdgcn_mfma_f32_16x16x32_bf16(a, b, zz, 0,0,0);
        int col = nt*16+lm;
        int jj = kc*32 + (col&31);
        float u1v = u1s[jj], u12v = u12s[jj];
        #pragma unroll
        for (int r=0;r<4;r++){
          int row = rb + r;
          float vT = (r<2) ? vA : vB;
          float cf;
          if (kc < q) cf = u12v;
          else {
            int T = q*32 + (row>>1);
            if (kc == q) cf = (jj<=T) ? u12v : ((jj==T+1) ? u1v : 0.f);
            else         cf = (jj==T+1) ? u1v : 0.f;
          }
          Fs[row*72+col] = f2bf(cf*vT*s[r]);
        }
      }
    }
    __syncthreads();
    #pragma unroll
    for (int r2=0;r2<2;r2++){
      bfv8 a = *(const bfv8*)&Fs[(w*16+lm)*72 + r2*32 + lq*8];
      #pragma unroll
      for (int nt=0;nt<4;nt++){
        bfv8 b = *(const bfv8*)&Xs[(nt*16+lm)*72 + r2*32 + lq*8];
        acc[nt] = __builtin_amdgcn_mfma_f32_16x16x32_bf16(a, b, acc[nt], 0,0,0);
      }
    }
    if (q == 3){
      #pragma unroll
      for (int r2=0;r2<2;r2++){
        bfv8 a = *(const bfv8*)&Xs[(w*16+lm)*72 + r2*32 + lq*8];
        #pragma unroll
        for (int nt2=0;nt2<2;nt2++){
          bfv8 b = *(const bfv8*)&Bsn[(nt2*16+lm)*72 + r2*32 + lq*8];
          acch[nt2] = __builtin_amdgcn_mfma_f32_16x16x32_bf16(a, b, acch[nt2], 0,0,0);
        }
      }
    }
    __syncthreads();
  }
  #pragma unroll
  for (int nt=0;nt<4;nt++){
    int p = nt*16+lm;
    #pragma unroll
    for (int r=0;r<4;r++){
      int row = w*16+lq*4+r;
      int T = q*32+(row>>1), r1 = row&1;
      ypr[((size_t)(l0+T)*16 + h)*128 + p*2+r1] = f2bf(acc[nt][r]);
    }
  }
  if (q == 3){
    #pragma unroll
    for (int nt2=0;nt2<2;nt2++){
      int n = nt2*16+lm;
      #pragma unroll
      for (int r=0;r<4;r++){
        int p = w*16+lq*4+r;
        hfin[(((size_t)c*16+h)*64 + p)*32 + n] = f2bf(acch[nt2][r]);
      }
    }
    if (tid == 0) dcb[c*16+h] = __expf(cs_l[127]);
  }
  if (q == 0 && h4 == 0 && tid < 128) csb[(c*4+g)*128 + tid] = cs_l[tid];
}

// ------- K8AF: fused inter-chunk scan + y_off (MFMA) + ydown (MFMA) + gates, per (c,h) ---------
__global__ void __launch_bounds__(256) k8af(
  const bf16* __restrict__ Cr, const bf16* __restrict__ hfin,
  const float* __restrict__ dcb, const float* __restrict__ csb,
  bf16* __restrict__ ypr, const bf16* __restrict__ WydT,
  const bf16* __restrict__ proj, const float* __restrict__ Dp)
{
  __shared__ __align__(16) char arena[52224];
  bf16* C2s = (bf16*)arena;              // [256*40] 20480 B (phase 1)
  bf16* hT  = (bf16*)(arena + 20480);    // [64*40]   5120 B (phase 1)
  float* cse = (float*)(arena + 25600);  // [128]      512 B (phase 1)
  bf16* Yf  = (bf16*)arena;              // [128*136] 34816 B (phase 2, aliases C2s/hT/cse)
  bf16* Wds = (bf16*)(arena + 34816);    // [64*136] 17408 B (both phases)
  int h = blockIdx.x, c = blockIdx.y;
  int g = h >> 2;
  int tid = threadIdx.x;
  int l0 = c*TCH;
  int w = tid>>6, lane = tid&63, lm = lane&15, lq = lane>>4;
  for (int e4 = tid; e4 < 2048; e4 += 256){
    int tl = e4>>4, c4 = (e4&15)*4;
    bf4v v = *(const bf4v*)&Cr[((size_t)(l0+tl)*4+g)*64 + c4];
    bf16 arr[4] = {v.x,v.y,v.z,v.w};
    #pragma unroll
    for (int i=0;i<4;i++){ int q6=c4+i; C2s[((tl<<1)|(q6&1))*40 + (q6>>1)] = arr[i]; }
  }
  for (int e = tid; e < 1024; e += 256){
    int qq = e>>4, k8 = (e&15)*8;
    *(bf8s*)&Wds[qq*136 + k8] = *(const bf8s*)&WydT[qq*128 + k8];
  }
  {
    int e0 = tid*8;
    float carry[8] = {};
    for (int j = 0; j < c; j++){
      float dc = dcb[j*16+h];
      float4 a = ldb4(&hfin[((size_t)j*16+h)*2048 + e0]);
      float4 b = ldb4(&hfin[((size_t)j*16+h)*2048 + e0 + 4]);
      carry[0]=carry[0]*dc+a.x; carry[1]=carry[1]*dc+a.y; carry[2]=carry[2]*dc+a.z; carry[3]=carry[3]*dc+a.w;
      carry[4]=carry[4]*dc+b.x; carry[5]=carry[5]*dc+b.y; carry[6]=carry[6]*dc+b.z; carry[7]=carry[7]*dc+b.w;
    }
    int p = e0>>5, n = e0&31;
    stb4(&hT[p*40+n],   make_float4(carry[0],carry[1],carry[2],carry[3]));
    stb4(&hT[p*40+n+4], make_float4(carry[4],carry[5],carry[6],carry[7]));
  }
  if (tid < 128) cse[tid] = __expf(csb[(c*4+g)*128 + tid]);
  __syncthreads();
  float yfull[4][4][4];
  fv4 zz = {0.f,0.f,0.f,0.f};
  #pragma unroll
  for (int mi=0;mi<4;mi++){
    int mt = w*4 + mi;
    bfv8 a = *(const bfv8*)&C2s[(mt*16+lm)*40 + lq*8];
    #pragma unroll
    for (int nt=0;nt<4;nt++){
      bfv8 b = *(const bfv8*)&hT[(nt*16+lm)*40 + lq*8];
      fv4 s = __builtin_amdgcn_mfma_f32_16x16x32_bf16(a, b, zz, 0,0,0);
      int p = nt*16+lm;
      #pragma unroll
      for (int r=0;r<4;r++){
        int row = mt*16+lq*4+r;
        int tl = row>>1, r1 = row&1;
        float yd = bf2f(ypr[((size_t)(l0+tl)*16 + h)*128 + p*2 + r1]);
        yfull[mi][nt][r] = yd + cse[tl]*s[r];
      }
    }
  }
  __syncthreads();
  #pragma unroll
  for (int mi=0;mi<4;mi++){
    int mt = w*4 + mi;
    #pragma unroll
    for (int nt=0;nt<4;nt++){
      int p = nt*16+lm;
      #pragma unroll
      for (int r=0;r<4;r++){
        int row = mt*16+lq*4+r;
        int tl = row>>1, r1 = row&1;
        Yf[tl*136 + p*2 + r1] = f2bf(yfull[mi][nt][r]);
      }
    }
  }
  __syncthreads();
  fv4 acc2[2][4] = {};
  #pragma unroll
  for (int kq=0;kq<4;kq++){
    #pragma unroll
    for (int m2=0;m2<2;m2++){
      bfv8 a = *(const bfv8*)&Yf[((w*2+m2)*16+lm)*136 + kq*32 + lq*8];
      #pragma unroll
      for (int nt2=0;nt2<4;nt2++){
        bfv8 b = *(const bfv8*)&Wds[(nt2*16+lm)*136 + kq*32 + lq*8];
        acc2[m2][nt2] = __builtin_amdgcn_mfma_f32_16x16x32_bf16(a, b, acc2[m2][nt2], 0,0,0);
      }
    }
  }
  float dv = Dp[h];
  #pragma unroll
  for (int m2=0;m2<2;m2++){
    #pragma unroll
    for (int nt2=0;nt2<4;nt2++){
      int qq = nt2*16+lm;
      #pragma unroll
      for (int r=0;r<4;r++){
        int tl = (w*2+m2)*16 + lq*4 + r;
        size_t lrow = (size_t)(l0+tl)*DPROJ;
        float x = bf2f(proj[lrow + 1024 + h*64 + qq]);
        float z = bf2f(proj[lrow + h*64 + qq]);
        float xs = x/(1.f+__expf(-x));
        float zs = z/(1.f+__expf(-z));
        float outv = (acc2[m2][nt2][r] + dv*xs)*zs;
        ypr[((size_t)(l0+tl)*16 + h)*128 + 64 + qq] = f2bf(outv);
      }
    }
  }
}

extern "C" void kernel_launch(void* const* d_in, const int* in_sizes, int n_in,
                              void* d_out, int out_size, void* d_ws, size_t ws_size,
                              hipStream_t stream) {
  const float* u       = (const float*)d_in[0];
  const float* W_in    = (const float*)d_in[1];
  const float* b_in    = (const float*)d_in[2];
  const float* W_xup   = (const float*)d_in[3];
  const float* W_ydown = (const float*)d_in[4];
  const float* A_log   = (const float*)d_in[5];
  const float* theta_l = (const float*)d_in[6];
  const float* D_p     = (const float*)d_in[7];
  const float* wB      = (const float*)d_in[8];
  const float* wC      = (const float*)d_in[9];
  const float* biasB   = (const float*)d_in[10];
  const float* biasC   = (const float*)d_in[11];
  const float* W_out   = (const float*)d_in[12];
  float* out = (float*)d_out;

  char* w = (char*)d_ws;
  bf16*  proj  = (bf16*)(w);                       // 10,518,528 B
  float* dlraw = (float*)(w + 10518528);           //     65,536 B
  float* dtb   = (float*)(w + 10584064);           //     32,768 B
  float* lamb  = (float*)(w + 10616832);           //     32,768 B
  float* csdt  = (float*)(w + 10649600);           //     32,768 B
  bf16*  Brb   = (bf16*)(w + 10682368);            //  1,048,576 B
  bf16*  Crb   = (bf16*)(w + 11730944);            //  1,048,576 B
  bf16*  xupb  = (bf16*)(w + 12779520);            //  8,388,608 B
  bf16*  hfin  = (bf16*)(w + 21168128);            //  1,048,576 B
  bf16*  WxupT = (bf16*)(w + 22216704);            //     16,384 B (slack after hfin)
  float* dcb   = (float*)(w + 23265280);           //      1,024 B
  float* csb   = (float*)(w + 23266304);           //     32,768 B
  bf16*  ypr   = (bf16*)(w + 23299072);            //  8,388,608 B
  bf16*  WinT  = (bf16*)(w + 23299072);            //  aliased over ypr (dead once k6y writes ypr)
  bf16*  WoutT = (bf16*)(w + 33784832);            //  1,048,576 B
  bf16*  WydT  = (bf16*)(w + 34833408);            //     16,384 B

  prep<<<1872,256,0,stream>>>(W_in, WinT, W_out, WoutT, W_ydown, WydT, W_xup, WxupT);
  gemm1_mfma<<<dim3(21,16),256,0,stream>>>(u, WinT, b_in, proj, dlraw);
  k23<<<1,1024,0,stream>>>(dlraw, dtb, lamb, csdt);
  k45x<<<512,256,0,stream>>>(proj, WxupT, xupb, wB, wC, biasB, biasC, theta_l, csdt, Brb, Crb);
  k6y<<<dim3(16,16,4),256,0,stream>>>(Brb, Crb, xupb, dtb, lamb, A_log, ypr, hfin, dcb, csb);
  k8af<<<dim3(16,16),256,0,stream>>>(Crb, hfin, dcb, csb, ypr, WydT, proj, D_p);
  gemmo_mfma<<<dim3(8,32),256,0,stream>>>(ypr, WoutT, out);
}

// Round 7
// 171.880 us; speedup vs baseline: 1.7825x; 1.0342x over previous
//
#include <hip/hip_runtime.h>
#include <hip/hip_bf16.h>

typedef __hip_bfloat16 bf16;
typedef __bf16 bfv8 __attribute__((ext_vector_type(8)));
typedef float fv4 __attribute__((ext_vector_type(4)));

__device__ __forceinline__ float bf2f(bf16 x){ return __bfloat162float(x); }
__device__ __forceinline__ bf16 f2bf(float x){ return __float2bfloat16(x); }
__device__ __forceinline__ float blo(unsigned u){ return __uint_as_float(u<<16); }
__device__ __forceinline__ unsigned short f2bfu(float x){ bf16 t = f2bf(x); return *(unsigned short*)&t; }
struct __align__(8) bf4v { bf16 x,y,z,w; };
struct __align__(16) bf8s { unsigned short u[8]; };
__device__ __forceinline__ float4 ldb4(const bf16* p){
  ushort4 u = *(const ushort4*)p;
  float4 r;
  r.x = __uint_as_float(((unsigned)u.x)<<16);
  r.y = __uint_as_float(((unsigned)u.y)<<16);
  r.z = __uint_as_float(((unsigned)u.z)<<16);
  r.w = __uint_as_float(((unsigned)u.w)<<16);
  return r;
}
__device__ __forceinline__ void stb4(bf16* p, float4 v){
  bf4v t; t.x=f2bf(v.x); t.y=f2bf(v.y); t.z=f2bf(v.z); t.w=f2bf(v.w);
  *(bf4v*)p = t;
}

#define L_SEQ 2048
#define DPROJ 2568
#define NCHUNK 16
#define TCH 128

// ---------------- prep: transpose W_in/W_out/W_ydown/W_xup, one dispatch ----------------
__device__ __forceinline__ void tbody(const float* __restrict__ in, bf16* __restrict__ out,
                                      int R, int C, int Cpad, int bx, int by, float (*t)[33])
{
  int c0 = bx*32, r0 = by*32;
  int tx = threadIdx.x & 31, ty = threadIdx.x >> 5;
  for (int i=0;i<32;i+=8){
    int r = r0+i+ty, cc = c0+tx;
    t[i+ty][tx] = (r<R && cc<C) ? in[(size_t)r*C+cc] : 0.f;
  }
  __syncthreads();
  for (int i=0;i<32;i+=8){
    int cc = c0+i+ty, r = r0+tx;
    if (cc<Cpad && r<R) out[(size_t)cc*R + r] = f2bf(t[tx][i+ty]);
  }
}

__global__ void prep(const float* __restrict__ Win, bf16* __restrict__ WinT,
                     const float* __restrict__ Wout, bf16* __restrict__ WoutT,
                     const float* __restrict__ Wyd, bf16* __restrict__ WydT,
                     const float* __restrict__ Wxup, bf16* __restrict__ WxupT)
{
  __shared__ float t[32][33];
  int b = blockIdx.x;
  if (b < 1344){
    tbody(Win, WinT, 512, DPROJ, 2688, b%84, b/84, t);
  } else if (b < 1856){
    int idx = b - 1344;
    tbody(Wout, WoutT, 1024, 512, 512, idx%16, idx/16, t);
  } else if (b < 1864){
    int idx = b - 1856;
    tbody(Wyd, WydT, 128, 64, 64, idx%2, idx/2, t);
  } else {
    int idx = b - 1864;
    tbody(Wxup, WxupT, 64, 128, 128, idx%4, idx/4, t);
  }
}

// ------- GEMM1 (MFMA, 128x128 tile, BK=64): proj = bf16(u) @ W_in + b_in; fp32 side for dt/lam --
__global__ void __launch_bounds__(256) gemm1_mfma(const float* __restrict__ A, const bf16* __restrict__ BT,
                                                  const float* __restrict__ bias, bf16* __restrict__ C,
                                                  float* __restrict__ side)
{
  const int K = 512;
  __shared__ __align__(16) bf16 As[128*72];
  __shared__ __align__(16) bf16 Bs[128*72];
  int tid = threadIdx.x;
  int col0 = blockIdx.x*128, row0 = blockIdx.y*128;
  int wid = tid>>6, lane = tid&63;
  int wm = (wid&1)*64, wn = (wid>>1)*64;
  int lm = lane&15, lq = lane>>4;
  fv4 acc[4][4] = {};
  for (int k0=0;k0<K;k0+=64){
    #pragma unroll
    for (int i=0;i<4;i++){
      int e = tid + i*256;
      int r = e>>3, k8 = (e&7)*8;
      float4 a0 = *(const float4*)&A[(size_t)(row0+r)*K + k0 + k8];
      float4 a1 = *(const float4*)&A[(size_t)(row0+r)*K + k0 + k8 + 4];
      stb4(&As[r*72+k8],   a0);
      stb4(&As[r*72+k8+4], a1);
      *(bf8s*)&Bs[r*72+k8] = *(const bf8s*)&BT[(size_t)(col0+r)*K + k0 + k8];
    }
    __syncthreads();
    #pragma unroll
    for (int ks=0;ks<2;ks++){
      bfv8 af[4], bfr[4];
      #pragma unroll
      for (int mf=0;mf<4;mf++) af[mf] = *(const bfv8*)&As[(wm+mf*16+lm)*72 + ks*32 + lq*8];
      #pragma unroll
      for (int nf=0;nf<4;nf++) bfr[nf] = *(const bfv8*)&Bs[(wn+nf*16+lm)*72 + ks*32 + lq*8];
      #pragma unroll
      for (int mf=0;mf<4;mf++)
        #pragma unroll
        for (int nf=0;nf<4;nf++)
          acc[mf][nf] = __builtin_amdgcn_mfma_f32_16x16x32_bf16(af[mf], bfr[nf], acc[mf][nf], 0,0,0);
    }
    __syncthreads();
  }
  #pragma unroll
  for (int mf=0;mf<4;mf++){
    #pragma unroll
    for (int nf=0;nf<4;nf++){
      int gcol = col0 + wn + nf*16 + lm;
      if (gcol < DPROJ){
        float bia = bias[gcol];
        #pragma unroll
        for (int r=0;r<4;r++){
          int grow = row0 + wm + mf*16 + lq*4 + r;
          float v = acc[mf][nf][r] + bia;
          C[(size_t)grow*DPROJ + gcol] = f2bf(v);
          if (gcol >= 2560) side[grow*8 + (gcol-2560)] = v;
        }
      }
    }
  }
}

// ------- GEMM_OUT (MFMA, BK=128): out(2048x512 fp32) = y2(interleaved ypr bf16) @ W_out --------
__global__ void __launch_bounds__(256) gemmo_mfma(const bf16* __restrict__ Yp, const bf16* __restrict__ BT,
                                                  float* __restrict__ C)
{
  const int K = 1024;
  __shared__ __align__(16) bf16 As[64*136];
  __shared__ __align__(16) bf16 Bs[64*136];
  int tid = threadIdx.x;
  int col0 = blockIdx.x*64, row0 = blockIdx.y*64;
  int wid = tid>>6, lane = tid&63;
  int wm = (wid&1)*32, wn = (wid>>1)*32;
  int lm = lane&15, lq = lane>>4;
  fv4 acc[2][2] = {};
  for (int k0=0;k0<K;k0+=128){
    #pragma unroll
    for (int i=0;i<4;i++){
      int e = tid + i*256;
      int m = e>>4, k8 = (e&15)*8;
      int kg = k0 + k8;
      *(bf8s*)&As[m*136+k8] = *(const bf8s*)&Yp[(size_t)(row0+m)*2048 + ((kg>>6)*128) + 64 + (kg&63)];
      *(bf8s*)&Bs[m*136+k8] = *(const bf8s*)&BT[(size_t)(col0+m)*K + kg];
    }
    __syncthreads();
    #pragma unroll
    for (int ks=0;ks<4;ks++){
      bfv8 af[2], bfr[2];
      #pragma unroll
      for (int mf=0;mf<2;mf++) af[mf] = *(const bfv8*)&As[(wm+mf*16+lm)*136 + ks*32 + lq*8];
      #pragma unroll
      for (int nf=0;nf<2;nf++) bfr[nf] = *(const bfv8*)&Bs[(wn+nf*16+lm)*136 + ks*32 + lq*8];
      #pragma unroll
      for (int mf=0;mf<2;mf++)
        #pragma unroll
        for (int nf=0;nf<2;nf++)
          acc[mf][nf] = __builtin_amdgcn_mfma_f32_16x16x32_bf16(af[mf], bfr[nf], acc[mf][nf], 0,0,0);
    }
    __syncthreads();
  }
  #pragma unroll
  for (int mf=0;mf<2;mf++)
    #pragma unroll
    for (int nf=0;nf<2;nf++){
      int gcol = col0 + wn + nf*16 + lm;
      #pragma unroll
      for (int r=0;r<4;r++){
        int grow = row0 + wm + mf*16 + lq*4 + r;
        C[(size_t)grow*512 + gcol] = acc[mf][nf][r];
      }
    }
}

// ---- K23: dt=softplus, lam=sigmoid, csdt=cumsum_l(dt). 1024 thr, 3-level parallel scan. ----
__global__ void __launch_bounds__(1024) k23(const float* __restrict__ dlraw, float* __restrict__ dtb,
                    float* __restrict__ lamb, float* __restrict__ csdt)
{
  __shared__ float wt[16][4];
  __shared__ float wo[16][4];
  int tid = threadIdx.x;
  int g = tid & 3, seg = tid >> 2;       // seg 0..255, 8 l each
  int lane = tid & 63, wave = tid >> 6;  // 16 waves
  float dt[8];
  float lsum = 0.f;
  #pragma unroll
  for (int i=0;i<8;i++){
    int l = seg*8 + i;
    float dr = dlraw[l*8 + g];
    float lr = dlraw[l*8 + 4 + g];
    float d = (dr > 15.f) ? dr : log1pf(__expf(dr));
    dt[i] = d;
    lsum += d;
    dtb[l*4+g] = d;
    lamb[l*4+g] = 1.f/(1.f+__expf(-lr));
  }
  // per-g inclusive scan across the wave (lanes stride 4 share g)
  float s = lsum;
  #pragma unroll
  for (int off=4; off<64; off<<=1){
    float v = __shfl_up(s, off);
    if (lane >= off) s += v;
  }
  if (lane >= 60) wt[wave][g] = s;       // lanes 60..63: per-(wave,g) totals
  __syncthreads();
  if (tid < 64){
    int w2 = tid >> 2, g2 = tid & 3;
    float r = 0.f;
    for (int j=0;j<w2;j++) r += wt[j][g2];
    wo[w2][g2] = r;
  }
  __syncthreads();
  float run = wo[wave][g] + (s - lsum);  // global exclusive prefix for this thread's 8 l
  #pragma unroll
  for (int i=0;i<8;i++){
    int l = seg*8 + i;
    run += dt[i];
    csdt[l*4+g] = run;
  }
}

// ------- K45X: fused {x_up MFMA GEMM} + {rmsnorm+RoPE}, block-split --------------------------
__global__ void __launch_bounds__(256) k45x(
  const bf16* __restrict__ proj, const bf16* __restrict__ WxupT, bf16* __restrict__ xup,
  const float* __restrict__ wB, const float* __restrict__ wC,
  const float* __restrict__ biasB, const float* __restrict__ biasC,
  const float* __restrict__ theta_log, const float* __restrict__ csdt,
  bf16* __restrict__ Br, bf16* __restrict__ Cr)
{
  __shared__ __align__(16) bf16 As[128*72];
  __shared__ __align__(16) bf16 Bs[128*72];
  int tid = threadIdx.x;
  if (blockIdx.x < 256){
    // ---- x_up = silu(x).reshape(32768,64) @ W_xup(64,128), one 128x128 tile ----
    int m0 = blockIdx.x*128;
    for (int e = tid; e < 1024; e += 256){
      int n = e>>3, k8 = (e&7)*8;
      *(bf8s*)&Bs[n*72 + k8] = *(const bf8s*)&WxupT[n*64 + k8];
    }
    for (int e = tid; e < 1024; e += 256){
      int r = e>>3, k8 = (e&7)*8;
      int m = m0 + r;
      int l = m >> 4, h = m & 15;
      bf8s v = *(const bf8s*)&proj[(size_t)l*DPROJ + 1024 + h*64 + k8];
      float s[8];
      #pragma unroll
      for (int j=0;j<8;j++){
        float x = blo((unsigned)v.u[j]);
        s[j] = x/(1.f+__expf(-x));
      }
      stb4(&As[r*72 + k8],     make_float4(s[0],s[1],s[2],s[3]));
      stb4(&As[r*72 + k8 + 4], make_float4(s[4],s[5],s[6],s[7]));
    }
    __syncthreads();
    int wid = tid>>6, lane = tid&63;
    int wm = (wid&1)*64, wn = (wid>>1)*64;
    int lm = lane&15, lq = lane>>4;
    fv4 acc[4][4] = {};
    #pragma unroll
    for (int kk=0;kk<64;kk+=32){
      bfv8 af[4], bfr[4];
      #pragma unroll
      for (int mf=0;mf<4;mf++) af[mf] = *(const bfv8*)&As[(wm+mf*16+lm)*72 + kk + lq*8];
      #pragma unroll
      for (int nf=0;nf<4;nf++) bfr[nf] = *(const bfv8*)&Bs[(wn+nf*16+lm)*72 + kk + lq*8];
      #pragma unroll
      for (int mf=0;mf<4;mf++)
        #pragma unroll
        for (int nf=0;nf<4;nf++)
          acc[mf][nf] = __builtin_amdgcn_mfma_f32_16x16x32_bf16(af[mf], bfr[nf], acc[mf][nf], 0,0,0);
    }
    #pragma unroll
    for (int mf=0;mf<4;mf++)
      #pragma unroll
      for (int nf=0;nf<4;nf++){
        int col = wn + nf*16 + lm;
        #pragma unroll
        for (int r=0;r<4;r++){
          int m = m0 + wm + mf*16 + lq*4 + r;
          xup[(size_t)m*128 + col] = f2bf(acc[mf][nf][r]);
        }
      }
  } else {
    // ---- rmsnorm+RoPE for B/C (8 l per block, shuffle-only) ----
    int g = tid >> 6, idx = tid & 63;
    int k = idx >> 2;
    bool is_im = (idx >> 1) & 1;
    float th = __expf(theta_log[g*16+k]);
    float wBv = wB[idx], wCv = wC[idx];
    float bBv = biasB[g*64+idx], bCv = biasC[g*64+idx];
    #pragma unroll
    for (int i=0;i<8;i++){
      int l = (blockIdx.x-256)*8 + i;
      const bf16* pr = proj + (size_t)l*DPROJ;
      float bv = bf2f(pr[2048 + g*64 + idx]);
      float cv = bf2f(pr[2304 + g*64 + idx]);
      float sb = bv*bv, sc = cv*cv;
      #pragma unroll
      for (int off=32; off; off>>=1){ sb += __shfl_xor(sb, off); sc += __shfl_xor(sc, off); }
      float rb = rsqrtf(sb*(1.f/64.f) + 1e-5f);
      float rc = rsqrtf(sc*(1.f/64.f) + 1e-5f);
      float bm = bv*rb*wBv + bBv;
      float cm = cv*rc*wCv + bCv;
      float ang = csdt[l*4+g] * th;
      float ca = cosf(ang), sa = sinf(ang);
      float bp = __shfl_xor(bm, 2);
      float cp = __shfl_xor(cm, 2);
      float bo = is_im ? (bp*sa + bm*ca) : (bm*ca - bp*sa);
      float co = is_im ? (cp*sa + cm*ca) : (cm*ca - cp*sa);
      Br[((size_t)l*4+g)*64 + idx] = f2bf(bo);
      Cr[((size_t)l*4+g)*64 + idx] = f2bf(co);
    }
  }
}

// ------- K6Y (MFMA): y_diag per (chunk, group, t-quarter, head); q==3 also emits h_final --------
// Staging vectorized (R5): Bs/Cs use s-pairing (s,s+2 same row adjacent cols -> ds_write_b32);
// Xs/Bsn use jj-pairing (adjacent cols jj,jj+1 -> b32). LDS contents bit-identical to scalar ver.
// NOTE R3: q-merged variant (1 block/CU) regressed 191->306us — keep 1024-block structure.
__global__ void __launch_bounds__(256) k6y(
  const bf16* __restrict__ Br, const bf16* __restrict__ Cr, const bf16* __restrict__ xup,
  const float* __restrict__ dtb, const float* __restrict__ lamb, const float* __restrict__ A_log,
  bf16* __restrict__ ypr, bf16* __restrict__ hfin, float* __restrict__ dcb, float* __restrict__ csb)
{
  __shared__ __align__(16) bf16 Cs[64*40];
  __shared__ __align__(16) bf16 Bs[64*40];
  __shared__ __align__(16) bf16 Bsn[32*72];
  __shared__ __align__(16) bf16 Fs[64*72];
  __shared__ __align__(16) bf16 Xs[64*72];
  __shared__ float dt_l[128], lam_l[128], cs_l[128];
  __shared__ float u1s[160], u12s[160], vs_[32];
  int bx = blockIdx.x; int g = bx & 3, q = bx >> 2;
  int c = blockIdx.y;
  int h4 = blockIdx.z;
  int h = g*4 + h4;
  int tid = threadIdx.x;
  int l0 = c*TCH;
  int w = tid>>6, lane = tid&63, lm = lane&15, lq = lane>>4;
  float Ah = -__expf(A_log[g]);
  float dt_prev = (c>0) ? dtb[(l0-1)*4+g] : 0.f;
  if (tid<128){ dt_l[tid] = dtb[(l0+tid)*4+g]; lam_l[tid] = lamb[(l0+tid)*4+g]; }
  __syncthreads();
  if (tid < 64){
    float a = dt_l[2*tid]*Ah, b = dt_l[2*tid+1]*Ah;
    float s = a + b;
    #pragma unroll
    for (int off=1; off<64; off<<=1){
      float v = __shfl_up(s, off);
      if (tid >= off) s += v;
    }
    cs_l[2*tid+1] = s;
    cs_l[2*tid]   = s - b;
  }
  __syncthreads();
  float ref = cs_l[q*32+16];
  if (tid < 160){
    int jj = tid;
    float u1v = 0.f, u2v = 0.f;
    if (jj>=1 && jj<=128) u1v = lam_l[jj-1]*dt_l[jj-1]*__expf(fminf(ref-cs_l[jj-1],60.f));
    if (jj<=127){ float dtx = (jj>=1)? dt_l[jj-1] : dt_prev; u2v = (1.f-lam_l[jj])*dtx*__expf(fminf(ref-cs_l[jj],60.f)); }
    u1s[jj] = u1v; u12s[jj] = u1v+u2v;
  }
  if (tid < 32) vs_[tid] = __expf(fminf(cs_l[q*32+tid]-ref,60.f));
  // Cs staging: 1 unit/thread = (1 tl x 8 s): bf8s load + 4 packed b32 writes
  {
    int tl = tid & 31, s8 = (tid >> 5)*8;
    bf8s v = *(const bf8s*)&Cr[((size_t)(l0+q*32+tl)*4+g)*64 + s8];
    int cb = s8>>1;
    *(unsigned*)&Cs[((tl<<1)|0)*40 + cb]   = (unsigned)v.u[0] | ((unsigned)v.u[2]<<16);
    *(unsigned*)&Cs[((tl<<1)|1)*40 + cb]   = (unsigned)v.u[1] | ((unsigned)v.u[3]<<16);
    *(unsigned*)&Cs[((tl<<1)|0)*40 + cb+2] = (unsigned)v.u[4] | ((unsigned)v.u[6]<<16);
    *(unsigned*)&Cs[((tl<<1)|1)*40 + cb+2] = (unsigned)v.u[5] | ((unsigned)v.u[7]<<16);
  }
  __syncthreads();   // covers u1s/u12s/vs_ and Cs before use
  float vfin = __expf(fminf(cs_l[127]-ref,60.f));
  fv4 acc[4] = {};
  fv4 acch[2] = {};
  int nch = (q+2 < 5) ? (q+2) : 5;
  for (int kc=0; kc<nch; kc++){
    // Bs staging: 1 unit/thread = (1 jj x 8 s)
    {
      int jjloc = tid & 31, s8 = (tid >> 5)*8;
      int jj = kc*32 + jjloc; int l = l0-1+jj;
      bf8s v = {};
      if (l >= 0 && jj <= 128) v = *(const bf8s*)&Br[((size_t)l*4+g)*64 + s8];
      int cb = s8>>1;
      *(unsigned*)&Bs[(jjloc)*40    + cb]   = (unsigned)v.u[0] | ((unsigned)v.u[2]<<16);
      *(unsigned*)&Bs[(32+jjloc)*40 + cb]   = (unsigned)v.u[1] | ((unsigned)v.u[3]<<16);
      *(unsigned*)&Bs[(jjloc)*40    + cb+2] = (unsigned)v.u[4] | ((unsigned)v.u[6]<<16);
      *(unsigned*)&Bs[(32+jjloc)*40 + cb+2] = (unsigned)v.u[5] | ((unsigned)v.u[7]<<16);
    }
    // Bsn staging (q==3): 1 unit/thread = (2 jj x 4 s)
    if (q == 3){
      int jj0 = (tid & 15)*2, s4 = (tid >> 4)*4;
      int jj = kc*32 + jj0;
      int lA = l0-1+jj;
      ushort4 b0 = {0,0,0,0}, b1 = {0,0,0,0};
      if (lA >= 0 && jj <= 128) b0 = *(const ushort4*)&Br[((size_t)lA*4+g)*64 + s4];
      if (jj+1 <= 128)          b1 = *(const ushort4*)&Br[((size_t)(lA+1)*4+g)*64 + s4];
      float g0 = vfin * u12s[jj], g1 = vfin * u12s[jj+1];
      unsigned short e0[4] = {b0.x,b0.y,b0.z,b0.w};
      unsigned short e1[4] = {b1.x,b1.y,b1.z,b1.w};
      #pragma unroll
      for (int i=0;i<4;i++){
        int s = s4+i;
        unsigned pk = (unsigned)f2bfu(g0*blo(e0[i])) | ((unsigned)f2bfu(g1*blo(e1[i]))<<16);
        *(unsigned*)&Bsn[(s>>1)*72 + (s&1)*32 + jj0] = pk;
      }
    }
    // Xs staging: 1 unit/thread = (2 jj x 8 p)
    {
      int jj0 = (tid & 15)*2, p8 = (tid >> 4)*8;
      int jj = kc*32 + jj0;
      int lA = l0-1+jj;
      bf8s v0 = {}, v1 = {};
      if (lA >= 0 && jj <= 128) v0 = *(const bf8s*)&xup[((size_t)lA*16 + h)*128 + p8];
      if (jj+1 <= 128)          v1 = *(const bf8s*)&xup[((size_t)(lA+1)*16 + h)*128 + p8];
      #pragma unroll
      for (int i=0;i<8;i++){
        int p = p8+i;
        *(unsigned*)&Xs[(p>>1)*72 + (p&1)*32 + jj0] = (unsigned)v0.u[i] | ((unsigned)v1.u[i]<<16);
      }
    }
    __syncthreads();
    {
      bfv8 a = *(const bfv8*)&Cs[(w*16+lm)*40 + lq*8];
      fv4 zz = {0.f,0.f,0.f,0.f};
      int rb = w*16 + lq*4;
      float vA = vs_[rb>>1];
      float vB = vs_[(rb>>1)+1];
      #pragma unroll
      for (int nt=0;nt<4;nt++){
        bfv8 b = *(const bfv8*)&Bs[(nt*16+lm)*40 + lq*8];
        fv4 s = __builtin_amdgcn_mfma_f32_16x16x32_bf16(a, b, zz, 0,0,0);
        int col = nt*16+lm;
        int jj = kc*32 + (col&31);
        float u1v = u1s[jj], u12v = u12s[jj];
        #pragma unroll
        for (int r=0;r<4;r++){
          int row = rb + r;
          float vT = (r<2) ? vA : vB;
          float cf;
          if (kc < q) cf = u12v;
          else {
            int T = q*32 + (row>>1);
            if (kc == q) cf = (jj<=T) ? u12v : ((jj==T+1) ? u1v : 0.f);
            else         cf = (jj==T+1) ? u1v : 0.f;
          }
          Fs[row*72+col] = f2bf(cf*vT*s[r]);
        }
      }
    }
    __syncthreads();
    #pragma unroll
    for (int r2=0;r2<2;r2++){
      bfv8 a = *(const bfv8*)&Fs[(w*16+lm)*72 + r2*32 + lq*8];
      #pragma unroll
      for (int nt=0;nt<4;nt++){
        bfv8 b = *(const bfv8*)&Xs[(nt*16+lm)*72 + r2*32 + lq*8];
        acc[nt] = __builtin_amdgcn_mfma_f32_16x16x32_bf16(a, b, acc[nt], 0,0,0);
      }
    }
    if (q == 3){
      #pragma unroll
      for (int r2=0;r2<2;r2++){
        bfv8 a = *(const bfv8*)&Xs[(w*16+lm)*72 + r2*32 + lq*8];
        #pragma unroll
        for (int nt2=0;nt2<2;nt2++){
          bfv8 b = *(const bfv8*)&Bsn[(nt2*16+lm)*72 + r2*32 + lq*8];
          acch[nt2] = __builtin_amdgcn_mfma_f32_16x16x32_bf16(a, b, acch[nt2], 0,0,0);
        }
      }
    }
    __syncthreads();
  }
  #pragma unroll
  for (int nt=0;nt<4;nt++){
    int p = nt*16+lm;
    #pragma unroll
    for (int r=0;r<4;r++){
      int row = w*16+lq*4+r;
      int T = q*32+(row>>1), r1 = row&1;
      ypr[((size_t)(l0+T)*16 + h)*128 + p*2+r1] = f2bf(acc[nt][r]);
    }
  }
  if (q == 3){
    #pragma unroll
    for (int nt2=0;nt2<2;nt2++){
      int n = nt2*16+lm;
      #pragma unroll
      for (int r=0;r<4;r++){
        int p = w*16+lq*4+r;
        hfin[(((size_t)c*16+h)*64 + p)*32 + n] = f2bf(acch[nt2][r]);
      }
    }
    if (tid == 0) dcb[c*16+h] = __expf(cs_l[127]);
  }
  if (q == 0 && h4 == 0 && tid < 128) csb[(c*4+g)*128 + tid] = cs_l[tid];
}

// ------- K8AF: fused inter-chunk scan + y_off (MFMA) + ydown (MFMA) + gates, per (c,h) ---------
__global__ void __launch_bounds__(256) k8af(
  const bf16* __restrict__ Cr, const bf16* __restrict__ hfin,
  const float* __restrict__ dcb, const float* __restrict__ csb,
  bf16* __restrict__ ypr, const bf16* __restrict__ WydT,
  const bf16* __restrict__ proj, const float* __restrict__ Dp)
{
  __shared__ __align__(16) char arena[52224];
  bf16* C2s = (bf16*)arena;              // [256*40] 20480 B (phase 1)
  bf16* hT  = (bf16*)(arena + 20480);    // [64*40]   5120 B (phase 1)
  float* cse = (float*)(arena + 25600);  // [128]      512 B (phase 1)
  bf16* Yf  = (bf16*)arena;              // [128*136] 34816 B (phase 2, aliases C2s/hT/cse)
  bf16* Wds = (bf16*)(arena + 34816);    // [64*136] 17408 B (both phases)
  int h = blockIdx.x, c = blockIdx.y;
  int g = h >> 2;
  int tid = threadIdx.x;
  int l0 = c*TCH;
  int w = tid>>6, lane = tid&63, lm = lane&15, lq = lane>>4;
  // C2s staging: 4 units/thread = (1 tl x 8 s) each: bf8s load + 4 packed b32 writes
  for (int u4 = tid; u4 < 1024; u4 += 256){
    int tl = u4>>3, s8 = (u4&7)*8;
    bf8s v = *(const bf8s*)&Cr[((size_t)(l0+tl)*4+g)*64 + s8];
    int cb = s8>>1;
    *(unsigned*)&C2s[((tl<<1)|0)*40 + cb]   = (unsigned)v.u[0] | ((unsigned)v.u[2]<<16);
    *(unsigned*)&C2s[((tl<<1)|1)*40 + cb]   = (unsigned)v.u[1] | ((unsigned)v.u[3]<<16);
    *(unsigned*)&C2s[((tl<<1)|0)*40 + cb+2] = (unsigned)v.u[4] | ((unsigned)v.u[6]<<16);
    *(unsigned*)&C2s[((tl<<1)|1)*40 + cb+2] = (unsigned)v.u[5] | ((unsigned)v.u[7]<<16);
  }
  for (int e = tid; e < 1024; e += 256){
    int qq = e>>4, k8 = (e&15)*8;
    *(bf8s*)&Wds[qq*136 + k8] = *(const bf8s*)&WydT[qq*128 + k8];
  }
  {
    int e0 = tid*8;
    float carry[8] = {};
    for (int j = 0; j < c; j++){
      float dc = dcb[j*16+h];
      float4 a = ldb4(&hfin[((size_t)j*16+h)*2048 + e0]);
      float4 b = ldb4(&hfin[((size_t)j*16+h)*2048 + e0 + 4]);
      carry[0]=carry[0]*dc+a.x; carry[1]=carry[1]*dc+a.y; carry[2]=carry[2]*dc+a.z; carry[3]=carry[3]*dc+a.w;
      carry[4]=carry[4]*dc+b.x; carry[5]=carry[5]*dc+b.y; carry[6]=carry[6]*dc+b.z; carry[7]=carry[7]*dc+b.w;
    }
    int p = e0>>5, n = e0&31;
    stb4(&hT[p*40+n],   make_float4(carry[0],carry[1],carry[2],carry[3]));
    stb4(&hT[p*40+n+4], make_float4(carry[4],carry[5],carry[6],carry[7]));
  }
  if (tid < 128) cse[tid] = __expf(csb[(c*4+g)*128 + tid]);
  __syncthreads();
  float yfull[4][4][4];
  fv4 zz = {0.f,0.f,0.f,0.f};
  #pragma unroll
  for (int mi=0;mi<4;mi++){
    int mt = w*4 + mi;
    bfv8 a = *(const bfv8*)&C2s[(mt*16+lm)*40 + lq*8];
    #pragma unroll
    for (int nt=0;nt<4;nt++){
      bfv8 b = *(const bfv8*)&hT[(nt*16+lm)*40 + lq*8];
      fv4 s = __builtin_amdgcn_mfma_f32_16x16x32_bf16(a, b, zz, 0,0,0);
      int p = nt*16+lm;
      #pragma unroll
      for (int r=0;r<4;r++){
        int row = mt*16+lq*4+r;
        int tl = row>>1, r1 = row&1;
        float yd = bf2f(ypr[((size_t)(l0+tl)*16 + h)*128 + p*2 + r1]);
        yfull[mi][nt][r] = yd + cse[tl]*s[r];
      }
    }
  }
  __syncthreads();
  #pragma unroll
  for (int mi=0;mi<4;mi++){
    int mt = w*4 + mi;
    #pragma unroll
    for (int nt=0;nt<4;nt++){
      int p = nt*16+lm;
      #pragma unroll
      for (int r=0;r<4;r++){
        int row = mt*16+lq*4+r;
        int tl = row>>1, r1 = row&1;
        Yf[tl*136 + p*2 + r1] = f2bf(yfull[mi][nt][r]);
      }
    }
  }
  __syncthreads();
  fv4 acc2[2][4] = {};
  #pragma unroll
  for (int kq=0;kq<4;kq++){
    #pragma unroll
    for (int m2=0;m2<2;m2++){
      bfv8 a = *(const bfv8*)&Yf[((w*2+m2)*16+lm)*136 + kq*32 + lq*8];
      #pragma unroll
      for (int nt2=0;nt2<4;nt2++){
        bfv8 b = *(const bfv8*)&Wds[(nt2*16+lm)*136 + kq*32 + lq*8];
        acc2[m2][nt2] = __builtin_amdgcn_mfma_f32_16x16x32_bf16(a, b, acc2[m2][nt2], 0,0,0);
      }
    }
  }
  float dv = Dp[h];
  #pragma unroll
  for (int m2=0;m2<2;m2++){
    #pragma unroll
    for (int nt2=0;nt2<4;nt2++){
      int qq = nt2*16+lm;
      #pragma unroll
      for (int r=0;r<4;r++){
        int tl = (w*2+m2)*16 + lq*4 + r;
        size_t lrow = (size_t)(l0+tl)*DPROJ;
        float x = bf2f(proj[lrow + 1024 + h*64 + qq]);
        float z = bf2f(proj[lrow + h*64 + qq]);
        float xs = x/(1.f+__expf(-x));
        float zs = z/(1.f+__expf(-z));
        float outv = (acc2[m2][nt2][r] + dv*xs)*zs;
        ypr[((size_t)(l0+tl)*16 + h)*128 + 64 + qq] = f2bf(outv);
      }
    }
  }
}

extern "C" void kernel_launch(void* const* d_in, const int* in_sizes, int n_in,
                              void* d_out, int out_size, void* d_ws, size_t ws_size,
                              hipStream_t stream) {
  const float* u       = (const float*)d_in[0];
  const float* W_in    = (const float*)d_in[1];
  const float* b_in    = (const float*)d_in[2];
  const float* W_xup   = (const float*)d_in[3];
  const float* W_ydown = (const float*)d_in[4];
  const float* A_log   = (const float*)d_in[5];
  const float* theta_l = (const float*)d_in[6];
  const float* D_p     = (const float*)d_in[7];
  const float* wB      = (const float*)d_in[8];
  const float* wC      = (const float*)d_in[9];
  const float* biasB   = (const float*)d_in[10];
  const float* biasC   = (const float*)d_in[11];
  const float* W_out   = (const float*)d_in[12];
  float* out = (float*)d_out;

  char* w = (char*)d_ws;
  bf16*  proj  = (bf16*)(w);                       // 10,518,528 B
  float* dlraw = (float*)(w + 10518528);           //     65,536 B
  float* dtb   = (float*)(w + 10584064);           //     32,768 B
  float* lamb  = (float*)(w + 10616832);           //     32,768 B
  float* csdt  = (float*)(w + 10649600);           //     32,768 B
  bf16*  Brb   = (bf16*)(w + 10682368);            //  1,048,576 B
  bf16*  Crb   = (bf16*)(w + 11730944);            //  1,048,576 B
  bf16*  xupb  = (bf16*)(w + 12779520);            //  8,388,608 B
  bf16*  hfin  = (bf16*)(w + 21168128);            //  1,048,576 B
  bf16*  WxupT = (bf16*)(w + 22216704);            //     16,384 B (slack after hfin)
  float* dcb   = (float*)(w + 23265280);           //      1,024 B
  float* csb   = (float*)(w + 23266304);           //     32,768 B
  bf16*  ypr   = (bf16*)(w + 23299072);            //  8,388,608 B
  bf16*  WinT  = (bf16*)(w + 23299072);            //  aliased over ypr (dead once k6y writes ypr)
  bf16*  WoutT = (bf16*)(w + 33784832);            //  1,048,576 B
  bf16*  WydT  = (bf16*)(w + 34833408);            //     16,384 B

  prep<<<1872,256,0,stream>>>(W_in, WinT, W_out, WoutT, W_ydown, WydT, W_xup, WxupT);
  gemm1_mfma<<<dim3(21,16),256,0,stream>>>(u, WinT, b_in, proj, dlraw);
  k23<<<1,1024,0,stream>>>(dlraw, dtb, lamb, csdt);
  k45x<<<512,256,0,stream>>>(proj, WxupT, xupb, wB, wC, biasB, biasC, theta_l, csdt, Brb, Crb);
  k6y<<<dim3(16,16,4),256,0,stream>>>(Brb, Crb, xupb, dtb, lamb, A_log, ypr, hfin, dcb, csb);
  k8af<<<dim3(16,16),256,0,stream>>>(Crb, hfin, dcb, csb, ypr, WydT, proj, D_p);
  gemmo_mfma<<<dim3(8,32),256,0,stream>>>(ypr, WoutT, out);
}

// Round 8
// 170.425 us; speedup vs baseline: 1.7977x; 1.0085x over previous
//
#include <hip/hip_runtime.h>
#include <hip/hip_bf16.h>

typedef __hip_bfloat16 bf16;
typedef __bf16 bfv8 __attribute__((ext_vector_type(8)));
typedef float fv4 __attribute__((ext_vector_type(4)));

__device__ __forceinline__ float bf2f(bf16 x){ return __bfloat162float(x); }
__device__ __forceinline__ bf16 f2bf(float x){ return __float2bfloat16(x); }
__device__ __forceinline__ float blo(unsigned u){ return __uint_as_float(u<<16); }
__device__ __forceinline__ unsigned short f2bfu(float x){ bf16 t = f2bf(x); return *(unsigned short*)&t; }
struct __align__(8) bf4v { bf16 x,y,z,w; };
struct __align__(16) bf8s { unsigned short u[8]; };
__device__ __forceinline__ float4 ldb4(const bf16* p){
  ushort4 u = *(const ushort4*)p;
  float4 r;
  r.x = __uint_as_float(((unsigned)u.x)<<16);
  r.y = __uint_as_float(((unsigned)u.y)<<16);
  r.z = __uint_as_float(((unsigned)u.z)<<16);
  r.w = __uint_as_float(((unsigned)u.w)<<16);
  return r;
}
__device__ __forceinline__ void stb4(bf16* p, float4 v){
  bf4v t; t.x=f2bf(v.x); t.y=f2bf(v.y); t.z=f2bf(v.z); t.w=f2bf(v.w);
  *(bf4v*)p = t;
}

#define L_SEQ 2048
#define DPROJ 2568
#define NCHUNK 16
#define TCH 128

// ---------------- prep: castU + transpose W_in/W_out/W_ydown/W_xup, one dispatch ----------------
__device__ __forceinline__ void tbody(const float* __restrict__ in, bf16* __restrict__ out,
                                      int R, int C, int Cpad, int bx, int by, float (*t)[33])
{
  int c0 = bx*32, r0 = by*32;
  int tx = threadIdx.x & 31, ty = threadIdx.x >> 5;
  for (int i=0;i<32;i+=8){
    int r = r0+i+ty, cc = c0+tx;
    t[i+ty][tx] = (r<R && cc<C) ? in[(size_t)r*C+cc] : 0.f;
  }
  __syncthreads();
  for (int i=0;i<32;i+=8){
    int cc = c0+i+ty, r = r0+tx;
    if (cc<Cpad && r<R) out[(size_t)cc*R + r] = f2bf(t[tx][i+ty]);
  }
}

__global__ void prep(const float* __restrict__ u, bf16* __restrict__ ubf,
                     const float* __restrict__ Win, bf16* __restrict__ WinT,
                     const float* __restrict__ Wout, bf16* __restrict__ WoutT,
                     const float* __restrict__ Wyd, bf16* __restrict__ WydT,
                     const float* __restrict__ Wxup, bf16* __restrict__ WxupT)
{
  __shared__ float t[32][33];
  int b = blockIdx.x;
  if (b < 1024){
    int i = (b*256 + threadIdx.x)*4;
    float4 v = *(const float4*)&u[i];
    stb4(&ubf[i], v);
  } else if (b < 2368){
    int idx = b - 1024;
    tbody(Win, WinT, 512, DPROJ, 2688, idx%84, idx/84, t);
  } else if (b < 2880){
    int idx = b - 2368;
    tbody(Wout, WoutT, 1024, 512, 512, idx%16, idx/16, t);
  } else if (b < 2888){
    int idx = b - 2880;
    tbody(Wyd, WydT, 128, 64, 64, idx%2, idx/2, t);
  } else {
    int idx = b - 2888;
    tbody(Wxup, WxupT, 64, 128, 128, idx%4, idx/4, t);
  }
}

// ------- GEMM1 (MFMA, 128x128 tile, BK=64): proj = ubf @ W_in + b_in; fp32 side for dt/lam ----
// R8: A staged from prep-cast bf16 (ubf) — halves A-panel re-read traffic (84->42 MB over 21
// N-tiles) and removes 16 cvt/thread/kstep of staging VALU.
__global__ void __launch_bounds__(256) gemm1_mfma(const bf16* __restrict__ A, const bf16* __restrict__ BT,
                                                  const float* __restrict__ bias, bf16* __restrict__ C,
                                                  float* __restrict__ side)
{
  const int K = 512;
  __shared__ __align__(16) bf16 As[128*72];
  __shared__ __align__(16) bf16 Bs[128*72];
  int tid = threadIdx.x;
  int col0 = blockIdx.x*128, row0 = blockIdx.y*128;
  int wid = tid>>6, lane = tid&63;
  int wm = (wid&1)*64, wn = (wid>>1)*64;
  int lm = lane&15, lq = lane>>4;
  fv4 acc[4][4] = {};
  for (int k0=0;k0<K;k0+=64){
    #pragma unroll
    for (int i=0;i<4;i++){
      int e = tid + i*256;
      int r = e>>3, k8 = (e&7)*8;
      *(bf8s*)&As[r*72+k8] = *(const bf8s*)&A[(size_t)(row0+r)*K + k0 + k8];
      *(bf8s*)&Bs[r*72+k8] = *(const bf8s*)&BT[(size_t)(col0+r)*K + k0 + k8];
    }
    __syncthreads();
    #pragma unroll
    for (int ks=0;ks<2;ks++){
      bfv8 af[4], bfr[4];
      #pragma unroll
      for (int mf=0;mf<4;mf++) af[mf] = *(const bfv8*)&As[(wm+mf*16+lm)*72 + ks*32 + lq*8];
      #pragma unroll
      for (int nf=0;nf<4;nf++) bfr[nf] = *(const bfv8*)&Bs[(wn+nf*16+lm)*72 + ks*32 + lq*8];
      #pragma unroll
      for (int mf=0;mf<4;mf++)
        #pragma unroll
        for (int nf=0;nf<4;nf++)
          acc[mf][nf] = __builtin_amdgcn_mfma_f32_16x16x32_bf16(af[mf], bfr[nf], acc[mf][nf], 0,0,0);
    }
    __syncthreads();
  }
  #pragma unroll
  for (int mf=0;mf<4;mf++){
    #pragma unroll
    for (int nf=0;nf<4;nf++){
      int gcol = col0 + wn + nf*16 + lm;
      if (gcol < DPROJ){
        float bia = bias[gcol];
        #pragma unroll
        for (int r=0;r<4;r++){
          int grow = row0 + wm + mf*16 + lq*4 + r;
          float v = acc[mf][nf][r] + bia;
          C[(size_t)grow*DPROJ + gcol] = f2bf(v);
          if (gcol >= 2560) side[grow*8 + (gcol-2560)] = v;
        }
      }
    }
  }
}

// ------- GEMM_OUT (MFMA, BK=128): out(2048x512 fp32) = y2(interleaved ypr bf16) @ W_out --------
__global__ void __launch_bounds__(256) gemmo_mfma(const bf16* __restrict__ Yp, const bf16* __restrict__ BT,
                                                  float* __restrict__ C)
{
  const int K = 1024;
  __shared__ __align__(16) bf16 As[64*136];
  __shared__ __align__(16) bf16 Bs[64*136];
  int tid = threadIdx.x;
  int col0 = blockIdx.x*64, row0 = blockIdx.y*64;
  int wid = tid>>6, lane = tid&63;
  int wm = (wid&1)*32, wn = (wid>>1)*32;
  int lm = lane&15, lq = lane>>4;
  fv4 acc[2][2] = {};
  for (int k0=0;k0<K;k0+=128){
    #pragma unroll
    for (int i=0;i<4;i++){
      int e = tid + i*256;
      int m = e>>4, k8 = (e&15)*8;
      int kg = k0 + k8;
      *(bf8s*)&As[m*136+k8] = *(const bf8s*)&Yp[(size_t)(row0+m)*2048 + ((kg>>6)*128) + 64 + (kg&63)];
      *(bf8s*)&Bs[m*136+k8] = *(const bf8s*)&BT[(size_t)(col0+m)*K + kg];
    }
    __syncthreads();
    #pragma unroll
    for (int ks=0;ks<4;ks++){
      bfv8 af[2], bfr[2];
      #pragma unroll
      for (int mf=0;mf<2;mf++) af[mf] = *(const bfv8*)&As[(wm+mf*16+lm)*136 + ks*32 + lq*8];
      #pragma unroll
      for (int nf=0;nf<2;nf++) bfr[nf] = *(const bfv8*)&Bs[(wn+nf*16+lm)*136 + ks*32 + lq*8];
      #pragma unroll
      for (int mf=0;mf<2;mf++)
        #pragma unroll
        for (int nf=0;nf<2;nf++)
          acc[mf][nf] = __builtin_amdgcn_mfma_f32_16x16x32_bf16(af[mf], bfr[nf], acc[mf][nf], 0,0,0);
    }
    __syncthreads();
  }
  #pragma unroll
  for (int mf=0;mf<2;mf++)
    #pragma unroll
    for (int nf=0;nf<2;nf++){
      int gcol = col0 + wn + nf*16 + lm;
      #pragma unroll
      for (int r=0;r<4;r++){
        int grow = row0 + wm + mf*16 + lq*4 + r;
        C[(size_t)grow*512 + gcol] = acc[mf][nf][r];
      }
    }
}

// ---- K23: dt=softplus, lam=sigmoid, csdt=cumsum_l(dt). 1024 thr, 3-level parallel scan. ----
__global__ void __launch_bounds__(1024) k23(const float* __restrict__ dlraw, float* __restrict__ dtb,
                    float* __restrict__ lamb, float* __restrict__ csdt)
{
  __shared__ float wt[16][4];
  __shared__ float wo[16][4];
  int tid = threadIdx.x;
  int g = tid & 3, seg = tid >> 2;       // seg 0..255, 8 l each
  int lane = tid & 63, wave = tid >> 6;  // 16 waves
  float dt[8];
  float lsum = 0.f;
  #pragma unroll
  for (int i=0;i<8;i++){
    int l = seg*8 + i;
    float dr = dlraw[l*8 + g];
    float lr = dlraw[l*8 + 4 + g];
    float d = (dr > 15.f) ? dr : log1pf(__expf(dr));
    dt[i] = d;
    lsum += d;
    dtb[l*4+g] = d;
    lamb[l*4+g] = 1.f/(1.f+__expf(-lr));
  }
  // per-g inclusive scan across the wave (lanes stride 4 share g)
  float s = lsum;
  #pragma unroll
  for (int off=4; off<64; off<<=1){
    float v = __shfl_up(s, off);
    if (lane >= off) s += v;
  }
  if (lane >= 60) wt[wave][g] = s;       // lanes 60..63: per-(wave,g) totals
  __syncthreads();
  if (tid < 64){
    int w2 = tid >> 2, g2 = tid & 3;
    float r = 0.f;
    for (int j=0;j<w2;j++) r += wt[j][g2];
    wo[w2][g2] = r;
  }
  __syncthreads();
  float run = wo[wave][g] + (s - lsum);  // global exclusive prefix for this thread's 8 l
  #pragma unroll
  for (int i=0;i<8;i++){
    int l = seg*8 + i;
    run += dt[i];
    csdt[l*4+g] = run;
  }
}

// ------- K45X: fused {x_up MFMA GEMM} + {rmsnorm+RoPE}, block-split --------------------------
__global__ void __launch_bounds__(256) k45x(
  const bf16* __restrict__ proj, const bf16* __restrict__ WxupT, bf16* __restrict__ xup,
  const float* __restrict__ wB, const float* __restrict__ wC,
  const float* __restrict__ biasB, const float* __restrict__ biasC,
  const float* __restrict__ theta_log, const float* __restrict__ csdt,
  bf16* __restrict__ Br, bf16* __restrict__ Cr)
{
  __shared__ __align__(16) bf16 As[128*72];
  __shared__ __align__(16) bf16 Bs[128*72];
  int tid = threadIdx.x;
  if (blockIdx.x < 256){
    // ---- x_up = silu(x).reshape(32768,64) @ W_xup(64,128), one 128x128 tile ----
    int m0 = blockIdx.x*128;
    for (int e = tid; e < 1024; e += 256){
      int n = e>>3, k8 = (e&7)*8;
      *(bf8s*)&Bs[n*72 + k8] = *(const bf8s*)&WxupT[n*64 + k8];
    }
    for (int e = tid; e < 1024; e += 256){
      int r = e>>3, k8 = (e&7)*8;
      int m = m0 + r;
      int l = m >> 4, h = m & 15;
      bf8s v = *(const bf8s*)&proj[(size_t)l*DPROJ + 1024 + h*64 + k8];
      float s[8];
      #pragma unroll
      for (int j=0;j<8;j++){
        float x = blo((unsigned)v.u[j]);
        s[j] = x/(1.f+__expf(-x));
      }
      stb4(&As[r*72 + k8],     make_float4(s[0],s[1],s[2],s[3]));
      stb4(&As[r*72 + k8 + 4], make_float4(s[4],s[5],s[6],s[7]));
    }
    __syncthreads();
    int wid = tid>>6, lane = tid&63;
    int wm = (wid&1)*64, wn = (wid>>1)*64;
    int lm = lane&15, lq = lane>>4;
    fv4 acc[4][4] = {};
    #pragma unroll
    for (int kk=0;kk<64;kk+=32){
      bfv8 af[4], bfr[4];
      #pragma unroll
      for (int mf=0;mf<4;mf++) af[mf] = *(const bfv8*)&As[(wm+mf*16+lm)*72 + kk + lq*8];
      #pragma unroll
      for (int nf=0;nf<4;nf++) bfr[nf] = *(const bfv8*)&Bs[(wn+nf*16+lm)*72 + kk + lq*8];
      #pragma unroll
      for (int mf=0;mf<4;mf++)
        #pragma unroll
        for (int nf=0;nf<4;nf++)
          acc[mf][nf] = __builtin_amdgcn_mfma_f32_16x16x32_bf16(af[mf], bfr[nf], acc[mf][nf], 0,0,0);
    }
    #pragma unroll
    for (int mf=0;mf<4;mf++)
      #pragma unroll
      for (int nf=0;nf<4;nf++){
        int col = wn + nf*16 + lm;
        #pragma unroll
        for (int r=0;r<4;r++){
          int m = m0 + wm + mf*16 + lq*4 + r;
          xup[(size_t)m*128 + col] = f2bf(acc[mf][nf][r]);
        }
      }
  } else {
    // ---- rmsnorm+RoPE for B/C (8 l per block, shuffle-only) ----
    int g = tid >> 6, idx = tid & 63;
    int k = idx >> 2;
    bool is_im = (idx >> 1) & 1;
    float th = __expf(theta_log[g*16+k]);
    float wBv = wB[idx], wCv = wC[idx];
    float bBv = biasB[g*64+idx], bCv = biasC[g*64+idx];
    #pragma unroll
    for (int i=0;i<8;i++){
      int l = (blockIdx.x-256)*8 + i;
      const bf16* pr = proj + (size_t)l*DPROJ;
      float bv = bf2f(pr[2048 + g*64 + idx]);
      float cv = bf2f(pr[2304 + g*64 + idx]);
      float sb = bv*bv, sc = cv*cv;
      #pragma unroll
      for (int off=32; off; off>>=1){ sb += __shfl_xor(sb, off); sc += __shfl_xor(sc, off); }
      float rb = rsqrtf(sb*(1.f/64.f) + 1e-5f);
      float rc = rsqrtf(sc*(1.f/64.f) + 1e-5f);
      float bm = bv*rb*wBv + bBv;
      float cm = cv*rc*wCv + bCv;
      float ang = csdt[l*4+g] * th;
      float ca = cosf(ang), sa = sinf(ang);
      float bp = __shfl_xor(bm, 2);
      float cp = __shfl_xor(cm, 2);
      float bo = is_im ? (bp*sa + bm*ca) : (bm*ca - bp*sa);
      float co = is_im ? (cp*sa + cm*ca) : (cm*ca - cp*sa);
      Br[((size_t)l*4+g)*64 + idx] = f2bf(bo);
      Cr[((size_t)l*4+g)*64 + idx] = f2bf(co);
    }
  }
}

// ------- K6Y (MFMA): y_diag per (chunk, group, t-quarter, head); q==3 also emits h_final --------
// R8: Fs is WAVE-PRIVATE (CB writes rows w*16.., FX reads same slice) -> the CB->FX barrier is
// replaced by a wave-local s_waitcnt lgkmcnt(0) (+sched_barrier per rule-18). 3->2 barriers/kc.
// NOTE R3: q-merged variant (1 block/CU) regressed 191->306us — keep 1024-block structure.
__global__ void __launch_bounds__(256) k6y(
  const bf16* __restrict__ Br, const bf16* __restrict__ Cr, const bf16* __restrict__ xup,
  const float* __restrict__ dtb, const float* __restrict__ lamb, const float* __restrict__ A_log,
  bf16* __restrict__ ypr, bf16* __restrict__ hfin, float* __restrict__ dcb, float* __restrict__ csb)
{
  __shared__ __align__(16) bf16 Cs[64*40];
  __shared__ __align__(16) bf16 Bs[64*40];
  __shared__ __align__(16) bf16 Bsn[32*72];
  __shared__ __align__(16) bf16 Fs[64*72];
  __shared__ __align__(16) bf16 Xs[64*72];
  __shared__ float dt_l[128], lam_l[128], cs_l[128];
  __shared__ float u1s[160], u12s[160], vs_[32];
  int bx = blockIdx.x; int g = bx & 3, q = bx >> 2;
  int c = blockIdx.y;
  int h4 = blockIdx.z;
  int h = g*4 + h4;
  int tid = threadIdx.x;
  int l0 = c*TCH;
  int w = tid>>6, lane = tid&63, lm = lane&15, lq = lane>>4;
  float Ah = -__expf(A_log[g]);
  float dt_prev = (c>0) ? dtb[(l0-1)*4+g] : 0.f;
  if (tid<128){ dt_l[tid] = dtb[(l0+tid)*4+g]; lam_l[tid] = lamb[(l0+tid)*4+g]; }
  __syncthreads();
  if (tid < 64){
    float a = dt_l[2*tid]*Ah, b = dt_l[2*tid+1]*Ah;
    float s = a + b;
    #pragma unroll
    for (int off=1; off<64; off<<=1){
      float v = __shfl_up(s, off);
      if (tid >= off) s += v;
    }
    cs_l[2*tid+1] = s;
    cs_l[2*tid]   = s - b;
  }
  __syncthreads();
  float ref = cs_l[q*32+16];
  if (tid < 160){
    int jj = tid;
    float u1v = 0.f, u2v = 0.f;
    if (jj>=1 && jj<=128) u1v = lam_l[jj-1]*dt_l[jj-1]*__expf(fminf(ref-cs_l[jj-1],60.f));
    if (jj<=127){ float dtx = (jj>=1)? dt_l[jj-1] : dt_prev; u2v = (1.f-lam_l[jj])*dtx*__expf(fminf(ref-cs_l[jj],60.f)); }
    u1s[jj] = u1v; u12s[jj] = u1v+u2v;
  }
  if (tid < 32) vs_[tid] = __expf(fminf(cs_l[q*32+tid]-ref,60.f));
  // Cs staging: 1 unit/thread = (1 tl x 8 s): bf8s load + 4 packed b32 writes
  {
    int tl = tid & 31, s8 = (tid >> 5)*8;
    bf8s v = *(const bf8s*)&Cr[((size_t)(l0+q*32+tl)*4+g)*64 + s8];
    int cb = s8>>1;
    *(unsigned*)&Cs[((tl<<1)|0)*40 + cb]   = (unsigned)v.u[0] | ((unsigned)v.u[2]<<16);
    *(unsigned*)&Cs[((tl<<1)|1)*40 + cb]   = (unsigned)v.u[1] | ((unsigned)v.u[3]<<16);
    *(unsigned*)&Cs[((tl<<1)|0)*40 + cb+2] = (unsigned)v.u[4] | ((unsigned)v.u[6]<<16);
    *(unsigned*)&Cs[((tl<<1)|1)*40 + cb+2] = (unsigned)v.u[5] | ((unsigned)v.u[7]<<16);
  }
  __syncthreads();   // covers u1s/u12s/vs_ and Cs before use
  float vfin = __expf(fminf(cs_l[127]-ref,60.f));
  fv4 acc[4] = {};
  fv4 acch[2] = {};
  int nch = (q+2 < 5) ? (q+2) : 5;
  for (int kc=0; kc<nch; kc++){
    // Bs staging: 1 unit/thread = (1 jj x 8 s)
    {
      int jjloc = tid & 31, s8 = (tid >> 5)*8;
      int jj = kc*32 + jjloc; int l = l0-1+jj;
      bf8s v = {};
      if (l >= 0 && jj <= 128) v = *(const bf8s*)&Br[((size_t)l*4+g)*64 + s8];
      int cb = s8>>1;
      *(unsigned*)&Bs[(jjloc)*40    + cb]   = (unsigned)v.u[0] | ((unsigned)v.u[2]<<16);
      *(unsigned*)&Bs[(32+jjloc)*40 + cb]   = (unsigned)v.u[1] | ((unsigned)v.u[3]<<16);
      *(unsigned*)&Bs[(jjloc)*40    + cb+2] = (unsigned)v.u[4] | ((unsigned)v.u[6]<<16);
      *(unsigned*)&Bs[(32+jjloc)*40 + cb+2] = (unsigned)v.u[5] | ((unsigned)v.u[7]<<16);
    }
    // Bsn staging (q==3): 1 unit/thread = (2 jj x 4 s)
    if (q == 3){
      int jj0 = (tid & 15)*2, s4 = (tid >> 4)*4;
      int jj = kc*32 + jj0;
      int lA = l0-1+jj;
      ushort4 b0 = {0,0,0,0}, b1 = {0,0,0,0};
      if (lA >= 0 && jj <= 128) b0 = *(const ushort4*)&Br[((size_t)lA*4+g)*64 + s4];
      if (jj+1 <= 128)          b1 = *(const ushort4*)&Br[((size_t)(lA+1)*4+g)*64 + s4];
      float g0 = vfin * u12s[jj], g1 = vfin * u12s[jj+1];
      unsigned short e0[4] = {b0.x,b0.y,b0.z,b0.w};
      unsigned short e1[4] = {b1.x,b1.y,b1.z,b1.w};
      #pragma unroll
      for (int i=0;i<4;i++){
        int s = s4+i;
        unsigned pk = (unsigned)f2bfu(g0*blo(e0[i])) | ((unsigned)f2bfu(g1*blo(e1[i]))<<16);
        *(unsigned*)&Bsn[(s>>1)*72 + (s&1)*32 + jj0] = pk;
      }
    }
    // Xs staging: 1 unit/thread = (2 jj x 8 p)
    {
      int jj0 = (tid & 15)*2, p8 = (tid >> 4)*8;
      int jj = kc*32 + jj0;
      int lA = l0-1+jj;
      bf8s v0 = {}, v1 = {};
      if (lA >= 0 && jj <= 128) v0 = *(const bf8s*)&xup[((size_t)lA*16 + h)*128 + p8];
      if (jj+1 <= 128)          v1 = *(const bf8s*)&xup[((size_t)(lA+1)*16 + h)*128 + p8];
      #pragma unroll
      for (int i=0;i<8;i++){
        int p = p8+i;
        *(unsigned*)&Xs[(p>>1)*72 + (p&1)*32 + jj0] = (unsigned)v0.u[i] | ((unsigned)v1.u[i]<<16);
      }
    }
    __syncthreads();
    {
      bfv8 a = *(const bfv8*)&Cs[(w*16+lm)*40 + lq*8];
      fv4 zz = {0.f,0.f,0.f,0.f};
      int rb = w*16 + lq*4;
      float vA = vs_[rb>>1];
      float vB = vs_[(rb>>1)+1];
      #pragma unroll
      for (int nt=0;nt<4;nt++){
        bfv8 b = *(const bfv8*)&Bs[(nt*16+lm)*40 + lq*8];
        fv4 s = __builtin_amdgcn_mfma_f32_16x16x32_bf16(a, b, zz, 0,0,0);
        int col = nt*16+lm;
        int jj = kc*32 + (col&31);
        float u1v = u1s[jj], u12v = u12s[jj];
        #pragma unroll
        for (int r=0;r<4;r++){
          int row = rb + r;
          float vT = (r<2) ? vA : vB;
          float cf;
          if (kc < q) cf = u12v;
          else {
            int T = q*32 + (row>>1);
            if (kc == q) cf = (jj<=T) ? u12v : ((jj==T+1) ? u1v : 0.f);
            else         cf = (jj==T+1) ? u1v : 0.f;
          }
          Fs[row*72+col] = f2bf(cf*vT*s[r]);
        }
      }
    }
    // Fs is wave-private (writer rows == reader rows per wave): wave-local wait, no barrier
    asm volatile("s_waitcnt lgkmcnt(0)" ::: "memory");
    __builtin_amdgcn_sched_barrier(0);
    #pragma unroll
    for (int r2=0;r2<2;r2++){
      bfv8 a = *(const bfv8*)&Fs[(w*16+lm)*72 + r2*32 + lq*8];
      #pragma unroll
      for (int nt=0;nt<4;nt++){
        bfv8 b = *(const bfv8*)&Xs[(nt*16+lm)*72 + r2*32 + lq*8];
        acc[nt] = __builtin_amdgcn_mfma_f32_16x16x32_bf16(a, b, acc[nt], 0,0,0);
      }
    }
    if (q == 3){
      #pragma unroll
      for (int r2=0;r2<2;r2++){
        bfv8 a = *(const bfv8*)&Xs[(w*16+lm)*72 + r2*32 + lq*8];
        #pragma unroll
        for (int nt2=0;nt2<2;nt2++){
          bfv8 b = *(const bfv8*)&Bsn[(nt2*16+lm)*72 + r2*32 + lq*8];
          acch[nt2] = __builtin_amdgcn_mfma_f32_16x16x32_bf16(a, b, acch[nt2], 0,0,0);
        }
      }
    }
    __syncthreads();
  }
  #pragma unroll
  for (int nt=0;nt<4;nt++){
    int p = nt*16+lm;
    #pragma unroll
    for (int r=0;r<4;r++){
      int row = w*16+lq*4+r;
      int T = q*32+(row>>1), r1 = row&1;
      ypr[((size_t)(l0+T)*16 + h)*128 + p*2+r1] = f2bf(acc[nt][r]);
    }
  }
  if (q == 3){
    #pragma unroll
    for (int nt2=0;nt2<2;nt2++){
      int n = nt2*16+lm;
      #pragma unroll
      for (int r=0;r<4;r++){
        int p = w*16+lq*4+r;
        hfin[(((size_t)c*16+h)*64 + p)*32 + n] = f2bf(acch[nt2][r]);
      }
    }
    if (tid == 0) dcb[c*16+h] = __expf(cs_l[127]);
  }
  if (q == 0 && h4 == 0 && tid < 128) csb[(c*4+g)*128 + tid] = cs_l[tid];
}

// ------- K8AF: fused inter-chunk scan + y_off (MFMA) + ydown (MFMA) + gates, per (c,h) ---------
// R8: arena re-laid into per-wave 8704B regions so Yf_w aliases ONLY its own wave's C2s_w.
// Yf is wave-private (writer tl-slice == reader tl-slice) -> 3 barriers reduce to 1 +
// wave-local lgkmcnt. Grid = 256 blocks = 1/CU, so the LDS growth (51->57.9 KB) is free.
__global__ void __launch_bounds__(256) k8af(
  const bf16* __restrict__ Cr, const bf16* __restrict__ hfin,
  const float* __restrict__ dcb, const float* __restrict__ csb,
  bf16* __restrict__ ypr, const bf16* __restrict__ WydT,
  const bf16* __restrict__ proj, const float* __restrict__ Dp)
{
  __shared__ __align__(16) char arena[57856];
  // [w*8704, +8704): wave-w region. Phase 1: C2s_w = 64 rows x 40 (5120 B). Phase 2: Yf_w =
  // 32 tl-rows x 136 (8704 B), aliases own C2s_w only.
  bf16* hT   = (bf16*)(arena + 34816);   // [64*40]  5120 B shared
  float* cse = (float*)(arena + 39936);  // [128]     512 B shared
  bf16* Wds  = (bf16*)(arena + 40448);   // [64*136] 17408 B shared
  int h = blockIdx.x, c = blockIdx.y;
  int g = h >> 2;
  int tid = threadIdx.x;
  int l0 = c*TCH;
  int w = tid>>6, lane = tid&63, lm = lane&15, lq = lane>>4;
  // C2s staging into per-wave regions: rows 2tl,2tl+1 -> region tl>>5, local rows (2tl)&63
  for (int u4 = tid; u4 < 1024; u4 += 256){
    int tl = u4>>3, s8 = (u4&7)*8;
    bf8s v = *(const bf8s*)&Cr[((size_t)(l0+tl)*4+g)*64 + s8];
    int cb = s8>>1;
    bf16* Cw = (bf16*)(arena + (tl>>5)*8704);
    int r0l = (tl<<1)&63;
    *(unsigned*)&Cw[(r0l  )*40 + cb]   = (unsigned)v.u[0] | ((unsigned)v.u[2]<<16);
    *(unsigned*)&Cw[(r0l|1)*40 + cb]   = (unsigned)v.u[1] | ((unsigned)v.u[3]<<16);
    *(unsigned*)&Cw[(r0l  )*40 + cb+2] = (unsigned)v.u[4] | ((unsigned)v.u[6]<<16);
    *(unsigned*)&Cw[(r0l|1)*40 + cb+2] = (unsigned)v.u[5] | ((unsigned)v.u[7]<<16);
  }
  for (int e = tid; e < 1024; e += 256){
    int qq = e>>4, k8 = (e&15)*8;
    *(bf8s*)&Wds[qq*136 + k8] = *(const bf8s*)&WydT[qq*128 + k8];
  }
  {
    int e0 = tid*8;
    float carry[8] = {};
    for (int j = 0; j < c; j++){
      float dc = dcb[j*16+h];
      float4 a = ldb4(&hfin[((size_t)j*16+h)*2048 + e0]);
      float4 b = ldb4(&hfin[((size_t)j*16+h)*2048 + e0 + 4]);
      carry[0]=carry[0]*dc+a.x; carry[1]=carry[1]*dc+a.y; carry[2]=carry[2]*dc+a.z; carry[3]=carry[3]*dc+a.w;
      carry[4]=carry[4]*dc+b.x; carry[5]=carry[5]*dc+b.y; carry[6]=carry[6]*dc+b.z; carry[7]=carry[7]*dc+b.w;
    }
    int p = e0>>5, n = e0&31;
    stb4(&hT[p*40+n],   make_float4(carry[0],carry[1],carry[2],carry[3]));
    stb4(&hT[p*40+n+4], make_float4(carry[4],carry[5],carry[6],carry[7]));
  }
  if (tid < 128) cse[tid] = __expf(csb[(c*4+g)*128 + tid]);
  __syncthreads();   // the ONLY barrier: C2s/hT/cse/Wds staged cooperatively
  bf16* C2w = (bf16*)(arena + w*8704);
  bf16* Yfw = (bf16*)(arena + w*8704);
  float yfull[4][4][4];
  fv4 zz = {0.f,0.f,0.f,0.f};
  #pragma unroll
  for (int mi=0;mi<4;mi++){
    bfv8 a = *(const bfv8*)&C2w[(mi*16+lm)*40 + lq*8];
    #pragma unroll
    for (int nt=0;nt<4;nt++){
      bfv8 b = *(const bfv8*)&hT[(nt*16+lm)*40 + lq*8];
      fv4 s = __builtin_amdgcn_mfma_f32_16x16x32_bf16(a, b, zz, 0,0,0);
      int p = nt*16+lm;
      #pragma unroll
      for (int r=0;r<4;r++){
        int row = (w*4+mi)*16+lq*4+r;
        int tl = row>>1, r1 = row&1;
        float yd = bf2f(ypr[((size_t)(l0+tl)*16 + h)*128 + p*2 + r1]);
        yfull[mi][nt][r] = yd + cse[tl]*s[r];
      }
    }
  }
  asm volatile("" ::: "memory");  // compile fence: keep C2s reads above Yf writes (alias)
  #pragma unroll
  for (int mi=0;mi<4;mi++){
    #pragma unroll
    for (int nt=0;nt<4;nt++){
      int p = nt*16+lm;
      #pragma unroll
      for (int r=0;r<4;r++){
        int row = (w*4+mi)*16+lq*4+r;
        int tl = row>>1, r1 = row&1;
        Yfw[(tl&31)*136 + p*2 + r1] = f2bf(yfull[mi][nt][r]);
      }
    }
  }
  // Yf is wave-private: wave-local wait, no barrier
  asm volatile("s_waitcnt lgkmcnt(0)" ::: "memory");
  __builtin_amdgcn_sched_barrier(0);
  fv4 acc2[2][4] = {};
  #pragma unroll
  for (int kq=0;kq<4;kq++){
    #pragma unroll
    for (int m2=0;m2<2;m2++){
      bfv8 a = *(const bfv8*)&Yfw[(m2*16+lm)*136 + kq*32 + lq*8];
      #pragma unroll
      for (int nt2=0;nt2<4;nt2++){
        bfv8 b = *(const bfv8*)&Wds[(nt2*16+lm)*136 + kq*32 + lq*8];
        acc2[m2][nt2] = __builtin_amdgcn_mfma_f32_16x16x32_bf16(a, b, acc2[m2][nt2], 0,0,0);
      }
    }
  }
  float dv = Dp[h];
  #pragma unroll
  for (int m2=0;m2<2;m2++){
    #pragma unroll
    for (int nt2=0;nt2<4;nt2++){
      int qq = nt2*16+lm;
      #pragma unroll
      for (int r=0;r<4;r++){
        int tl = (w*2+m2)*16 + lq*4 + r;
        size_t lrow = (size_t)(l0+tl)*DPROJ;
        float x = bf2f(proj[lrow + 1024 + h*64 + qq]);
        float z = bf2f(proj[lrow + h*64 + qq]);
        float xs = x/(1.f+__expf(-x));
        float zs = z/(1.f+__expf(-z));
        float outv = (acc2[m2][nt2][r] + dv*xs)*zs;
        ypr[((size_t)(l0+tl)*16 + h)*128 + 64 + qq] = f2bf(outv);
      }
    }
  }
}

extern "C" void kernel_launch(void* const* d_in, const int* in_sizes, int n_in,
                              void* d_out, int out_size, void* d_ws, size_t ws_size,
                              hipStream_t stream) {
  const float* u       = (const float*)d_in[0];
  const float* W_in    = (const float*)d_in[1];
  const float* b_in    = (const float*)d_in[2];
  const float* W_xup   = (const float*)d_in[3];
  const float* W_ydown = (const float*)d_in[4];
  const float* A_log   = (const float*)d_in[5];
  const float* theta_l = (const float*)d_in[6];
  const float* D_p     = (const float*)d_in[7];
  const float* wB      = (const float*)d_in[8];
  const float* wC      = (const float*)d_in[9];
  const float* biasB   = (const float*)d_in[10];
  const float* biasC   = (const float*)d_in[11];
  const float* W_out   = (const float*)d_in[12];
  float* out = (float*)d_out;

  char* w = (char*)d_ws;
  bf16*  proj  = (bf16*)(w);                       // 10,518,528 B
  float* dlraw = (float*)(w + 10518528);           //     65,536 B
  float* dtb   = (float*)(w + 10584064);           //     32,768 B
  float* lamb  = (float*)(w + 10616832);           //     32,768 B
  float* csdt  = (float*)(w + 10649600);           //     32,768 B
  bf16*  Brb   = (bf16*)(w + 10682368);            //  1,048,576 B
  bf16*  Crb   = (bf16*)(w + 11730944);            //  1,048,576 B
  bf16*  xupb  = (bf16*)(w + 12779520);            //  8,388,608 B
  bf16*  hfin  = (bf16*)(w + 21168128);            //  1,048,576 B
  bf16*  WxupT = (bf16*)(w + 22216704);            //     16,384 B (slack after hfin)
  float* dcb   = (float*)(w + 23265280);           //      1,024 B
  float* csb   = (float*)(w + 23266304);           //     32,768 B
  bf16*  ypr   = (bf16*)(w + 23299072);            //  8,388,608 B
  bf16*  WinT  = (bf16*)(w + 23299072);            //  aliased over ypr (dead once k6y writes ypr)
  bf16*  ubf   = (bf16*)(w + 31687680);            //  2,097,152 B
  bf16*  WoutT = (bf16*)(w + 33784832);            //  1,048,576 B
  bf16*  WydT  = (bf16*)(w + 34833408);            //     16,384 B

  prep<<<2896,256,0,stream>>>(u, ubf, W_in, WinT, W_out, WoutT, W_ydown, WydT, W_xup, WxupT);
  gemm1_mfma<<<dim3(21,16),256,0,stream>>>(ubf, WinT, b_in, proj, dlraw);
  k23<<<1,1024,0,stream>>>(dlraw, dtb, lamb, csdt);
  k45x<<<512,256,0,stream>>>(proj, WxupT, xupb, wB, wC, biasB, biasC, theta_l, csdt, Brb, Crb);
  k6y<<<dim3(16,16,4),256,0,stream>>>(Brb, Crb, xupb, dtb, lamb, A_log, ypr, hfin, dcb, csb);
  k8af<<<dim3(16,16),256,0,stream>>>(Crb, hfin, dcb, csb, ypr, WydT, proj, D_p);
  gemmo_mfma<<<dim3(8,32),256,0,stream>>>(ypr, WoutT, out);
}

// Round 9
// 166.277 us; speedup vs baseline: 1.8426x; 1.0249x over previous
//
#include <hip/hip_runtime.h>
#include <hip/hip_bf16.h>

typedef __hip_bfloat16 bf16;
typedef __bf16 bfv8 __attribute__((ext_vector_type(8)));
typedef float fv4 __attribute__((ext_vector_type(4)));

__device__ __forceinline__ float bf2f(bf16 x){ return __bfloat162float(x); }
__device__ __forceinline__ bf16 f2bf(float x){ return __float2bfloat16(x); }
__device__ __forceinline__ float blo(unsigned u){ return __uint_as_float(u<<16); }
__device__ __forceinline__ unsigned short f2bfu(float x){ bf16 t = f2bf(x); return *(unsigned short*)&t; }
struct __align__(8) bf4v { bf16 x,y,z,w; };
struct __align__(16) bf8s { unsigned short u[8]; };
__device__ __forceinline__ float4 ldb4(const bf16* p){
  ushort4 u = *(const ushort4*)p;
  float4 r;
  r.x = __uint_as_float(((unsigned)u.x)<<16);
  r.y = __uint_as_float(((unsigned)u.y)<<16);
  r.z = __uint_as_float(((unsigned)u.z)<<16);
  r.w = __uint_as_float(((unsigned)u.w)<<16);
  return r;
}
__device__ __forceinline__ void stb4(bf16* p, float4 v){
  bf4v t; t.x=f2bf(v.x); t.y=f2bf(v.y); t.z=f2bf(v.z); t.w=f2bf(v.w);
  *(bf4v*)p = t;
}

#define L_SEQ 2048
#define DPROJ 2568
#define NCHUNK 16
#define TCH 128

// ---------------- prep: castU + transpose W_in/W_out/W_ydown/W_xup, one dispatch ----------------
__device__ __forceinline__ void tbody(const float* __restrict__ in, bf16* __restrict__ out,
                                      int R, int C, int Cpad, int bx, int by, float (*t)[33])
{
  int c0 = bx*32, r0 = by*32;
  int tx = threadIdx.x & 31, ty = threadIdx.x >> 5;
  for (int i=0;i<32;i+=8){
    int r = r0+i+ty, cc = c0+tx;
    t[i+ty][tx] = (r<R && cc<C) ? in[(size_t)r*C+cc] : 0.f;
  }
  __syncthreads();
  for (int i=0;i<32;i+=8){
    int cc = c0+i+ty, r = r0+tx;
    if (cc<Cpad && r<R) out[(size_t)cc*R + r] = f2bf(t[tx][i+ty]);
  }
}

__global__ void prep(const float* __restrict__ u, bf16* __restrict__ ubf,
                     const float* __restrict__ Win, bf16* __restrict__ WinT,
                     const float* __restrict__ Wout, bf16* __restrict__ WoutT,
                     const float* __restrict__ Wyd, bf16* __restrict__ WydT,
                     const float* __restrict__ Wxup, bf16* __restrict__ WxupT)
{
  __shared__ float t[32][33];
  int b = blockIdx.x;
  if (b < 1024){
    int i = (b*256 + threadIdx.x)*4;
    float4 v = *(const float4*)&u[i];
    stb4(&ubf[i], v);
  } else if (b < 2368){
    int idx = b - 1024;
    tbody(Win, WinT, 512, DPROJ, 2688, idx%84, idx/84, t);
  } else if (b < 2880){
    int idx = b - 2368;
    tbody(Wout, WoutT, 1024, 512, 512, idx%16, idx/16, t);
  } else if (b < 2888){
    int idx = b - 2880;
    tbody(Wyd, WydT, 128, 64, 64, idx%2, idx/2, t);
  } else {
    int idx = b - 2888;
    tbody(Wxup, WxupT, 64, 128, 128, idx%4, idx/4, t);
  }
}

// ------- GEMM1 (MFMA, 128x128 tile, BK=64): proj = ubf @ W_in + b_in; fp32 side for dt/lam ----
__global__ void __launch_bounds__(256) gemm1_mfma(const bf16* __restrict__ A, const bf16* __restrict__ BT,
                                                  const float* __restrict__ bias, bf16* __restrict__ C,
                                                  float* __restrict__ side)
{
  const int K = 512;
  __shared__ __align__(16) bf16 As[128*72];
  __shared__ __align__(16) bf16 Bs[128*72];
  int tid = threadIdx.x;
  int col0 = blockIdx.x*128, row0 = blockIdx.y*128;
  int wid = tid>>6, lane = tid&63;
  int wm = (wid&1)*64, wn = (wid>>1)*64;
  int lm = lane&15, lq = lane>>4;
  fv4 acc[4][4] = {};
  for (int k0=0;k0<K;k0+=64){
    #pragma unroll
    for (int i=0;i<4;i++){
      int e = tid + i*256;
      int r = e>>3, k8 = (e&7)*8;
      *(bf8s*)&As[r*72+k8] = *(const bf8s*)&A[(size_t)(row0+r)*K + k0 + k8];
      *(bf8s*)&Bs[r*72+k8] = *(const bf8s*)&BT[(size_t)(col0+r)*K + k0 + k8];
    }
    __syncthreads();
    #pragma unroll
    for (int ks=0;ks<2;ks++){
      bfv8 af[4], bfr[4];
      #pragma unroll
      for (int mf=0;mf<4;mf++) af[mf] = *(const bfv8*)&As[(wm+mf*16+lm)*72 + ks*32 + lq*8];
      #pragma unroll
      for (int nf=0;nf<4;nf++) bfr[nf] = *(const bfv8*)&Bs[(wn+nf*16+lm)*72 + ks*32 + lq*8];
      #pragma unroll
      for (int mf=0;mf<4;mf++)
        #pragma unroll
        for (int nf=0;nf<4;nf++)
          acc[mf][nf] = __builtin_amdgcn_mfma_f32_16x16x32_bf16(af[mf], bfr[nf], acc[mf][nf], 0,0,0);
    }
    __syncthreads();
  }
  #pragma unroll
  for (int mf=0;mf<4;mf++){
    #pragma unroll
    for (int nf=0;nf<4;nf++){
      int gcol = col0 + wn + nf*16 + lm;
      if (gcol < DPROJ){
        float bia = bias[gcol];
        #pragma unroll
        for (int r=0;r<4;r++){
          int grow = row0 + wm + mf*16 + lq*4 + r;
          float v = acc[mf][nf][r] + bia;
          C[(size_t)grow*DPROJ + gcol] = f2bf(v);
          if (gcol >= 2560) side[grow*8 + (gcol-2560)] = v;
        }
      }
    }
  }
}

// ------- GEMM_OUT (MFMA, BK=128): out(2048x512 fp32) = y2(interleaved ypr bf16) @ W_out --------
__global__ void __launch_bounds__(256) gemmo_mfma(const bf16* __restrict__ Yp, const bf16* __restrict__ BT,
                                                  float* __restrict__ C)
{
  const int K = 1024;
  __shared__ __align__(16) bf16 As[64*136];
  __shared__ __align__(16) bf16 Bs[64*136];
  int tid = threadIdx.x;
  int col0 = blockIdx.x*64, row0 = blockIdx.y*64;
  int wid = tid>>6, lane = tid&63;
  int wm = (wid&1)*32, wn = (wid>>1)*32;
  int lm = lane&15, lq = lane>>4;
  fv4 acc[2][2] = {};
  for (int k0=0;k0<K;k0+=128){
    #pragma unroll
    for (int i=0;i<4;i++){
      int e = tid + i*256;
      int m = e>>4, k8 = (e&15)*8;
      int kg = k0 + k8;
      *(bf8s*)&As[m*136+k8] = *(const bf8s*)&Yp[(size_t)(row0+m)*2048 + ((kg>>6)*128) + 64 + (kg&63)];
      *(bf8s*)&Bs[m*136+k8] = *(const bf8s*)&BT[(size_t)(col0+m)*K + kg];
    }
    __syncthreads();
    #pragma unroll
    for (int ks=0;ks<4;ks++){
      bfv8 af[2], bfr[2];
      #pragma unroll
      for (int mf=0;mf<2;mf++) af[mf] = *(const bfv8*)&As[(wm+mf*16+lm)*136 + ks*32 + lq*8];
      #pragma unroll
      for (int nf=0;nf<2;nf++) bfr[nf] = *(const bfv8*)&Bs[(wn+nf*16+lm)*136 + ks*32 + lq*8];
      #pragma unroll
      for (int mf=0;mf<2;mf++)
        #pragma unroll
        for (int nf=0;nf<2;nf++)
          acc[mf][nf] = __builtin_amdgcn_mfma_f32_16x16x32_bf16(af[mf], bfr[nf], acc[mf][nf], 0,0,0);
    }
    __syncthreads();
  }
  #pragma unroll
  for (int mf=0;mf<2;mf++)
    #pragma unroll
    for (int nf=0;nf<2;nf++){
      int gcol = col0 + wn + nf*16 + lm;
      #pragma unroll
      for (int r=0;r<4;r++){
        int grow = row0 + wm + mf*16 + lq*4 + r;
        C[(size_t)grow*512 + gcol] = acc[mf][nf][r];
      }
    }
}

// ---- K23: dt=softplus, lam=sigmoid, csdt=cumsum_l(dt). 1024 thr, 3-level parallel scan. ----
__global__ void __launch_bounds__(1024) k23(const float* __restrict__ dlraw, float* __restrict__ dtb,
                    float* __restrict__ lamb, float* __restrict__ csdt)
{
  __shared__ float wt[16][4];
  __shared__ float wo[16][4];
  int tid = threadIdx.x;
  int g = tid & 3, seg = tid >> 2;       // seg 0..255, 8 l each
  int lane = tid & 63, wave = tid >> 6;  // 16 waves
  float dt[8];
  float lsum = 0.f;
  #pragma unroll
  for (int i=0;i<8;i++){
    int l = seg*8 + i;
    float dr = dlraw[l*8 + g];
    float lr = dlraw[l*8 + 4 + g];
    float d = (dr > 15.f) ? dr : log1pf(__expf(dr));
    dt[i] = d;
    lsum += d;
    dtb[l*4+g] = d;
    lamb[l*4+g] = 1.f/(1.f+__expf(-lr));
  }
  // per-g inclusive scan across the wave (lanes stride 4 share g)
  float s = lsum;
  #pragma unroll
  for (int off=4; off<64; off<<=1){
    float v = __shfl_up(s, off);
    if (lane >= off) s += v;
  }
  if (lane >= 60) wt[wave][g] = s;       // lanes 60..63: per-(wave,g) totals
  __syncthreads();
  if (tid < 64){
    int w2 = tid >> 2, g2 = tid & 3;
    float r = 0.f;
    for (int j=0;j<w2;j++) r += wt[j][g2];
    wo[w2][g2] = r;
  }
  __syncthreads();
  float run = wo[wave][g] + (s - lsum);  // global exclusive prefix for this thread's 8 l
  #pragma unroll
  for (int i=0;i<8;i++){
    int l = seg*8 + i;
    run += dt[i];
    csdt[l*4+g] = run;
  }
}

// ------- K45X: fused {x_up MFMA GEMM} + {rmsnorm+RoPE}, block-split --------------------------
__global__ void __launch_bounds__(256) k45x(
  const bf16* __restrict__ proj, const bf16* __restrict__ WxupT, bf16* __restrict__ xup,
  const float* __restrict__ wB, const float* __restrict__ wC,
  const float* __restrict__ biasB, const float* __restrict__ biasC,
  const float* __restrict__ theta_log, const float* __restrict__ csdt,
  bf16* __restrict__ Br, bf16* __restrict__ Cr)
{
  __shared__ __align__(16) bf16 As[128*72];
  __shared__ __align__(16) bf16 Bs[128*72];
  int tid = threadIdx.x;
  if (blockIdx.x < 256){
    // ---- x_up = silu(x).reshape(32768,64) @ W_xup(64,128), one 128x128 tile ----
    int m0 = blockIdx.x*128;
    for (int e = tid; e < 1024; e += 256){
      int n = e>>3, k8 = (e&7)*8;
      *(bf8s*)&Bs[n*72 + k8] = *(const bf8s*)&WxupT[n*64 + k8];
    }
    for (int e = tid; e < 1024; e += 256){
      int r = e>>3, k8 = (e&7)*8;
      int m = m0 + r;
      int l = m >> 4, h = m & 15;
      bf8s v = *(const bf8s*)&proj[(size_t)l*DPROJ + 1024 + h*64 + k8];
      float s[8];
      #pragma unroll
      for (int j=0;j<8;j++){
        float x = blo((unsigned)v.u[j]);
        s[j] = x/(1.f+__expf(-x));
      }
      stb4(&As[r*72 + k8],     make_float4(s[0],s[1],s[2],s[3]));
      stb4(&As[r*72 + k8 + 4], make_float4(s[4],s[5],s[6],s[7]));
    }
    __syncthreads();
    int wid = tid>>6, lane = tid&63;
    int wm = (wid&1)*64, wn = (wid>>1)*64;
    int lm = lane&15, lq = lane>>4;
    fv4 acc[4][4] = {};
    #pragma unroll
    for (int kk=0;kk<64;kk+=32){
      bfv8 af[4], bfr[4];
      #pragma unroll
      for (int mf=0;mf<4;mf++) af[mf] = *(const bfv8*)&As[(wm+mf*16+lm)*72 + kk + lq*8];
      #pragma unroll
      for (int nf=0;nf<4;nf++) bfr[nf] = *(const bfv8*)&Bs[(wn+nf*16+lm)*72 + kk + lq*8];
      #pragma unroll
      for (int mf=0;mf<4;mf++)
        #pragma unroll
        for (int nf=0;nf<4;nf++)
          acc[mf][nf] = __builtin_amdgcn_mfma_f32_16x16x32_bf16(af[mf], bfr[nf], acc[mf][nf], 0,0,0);
    }
    #pragma unroll
    for (int mf=0;mf<4;mf++)
      #pragma unroll
      for (int nf=0;nf<4;nf++){
        int col = wn + nf*16 + lm;
        #pragma unroll
        for (int r=0;r<4;r++){
          int m = m0 + wm + mf*16 + lq*4 + r;
          xup[(size_t)m*128 + col] = f2bf(acc[mf][nf][r]);
        }
      }
  } else {
    // ---- rmsnorm+RoPE for B/C (8 l per block, shuffle-only) ----
    int g = tid >> 6, idx = tid & 63;
    int k = idx >> 2;
    bool is_im = (idx >> 1) & 1;
    float th = __expf(theta_log[g*16+k]);
    float wBv = wB[idx], wCv = wC[idx];
    float bBv = biasB[g*64+idx], bCv = biasC[g*64+idx];
    #pragma unroll
    for (int i=0;i<8;i++){
      int l = (blockIdx.x-256)*8 + i;
      const bf16* pr = proj + (size_t)l*DPROJ;
      float bv = bf2f(pr[2048 + g*64 + idx]);
      float cv = bf2f(pr[2304 + g*64 + idx]);
      float sb = bv*bv, sc = cv*cv;
      #pragma unroll
      for (int off=32; off; off>>=1){ sb += __shfl_xor(sb, off); sc += __shfl_xor(sc, off); }
      float rb = rsqrtf(sb*(1.f/64.f) + 1e-5f);
      float rc = rsqrtf(sc*(1.f/64.f) + 1e-5f);
      float bm = bv*rb*wBv + bBv;
      float cm = cv*rc*wCv + bCv;
      float ang = csdt[l*4+g] * th;
      float ca = cosf(ang), sa = sinf(ang);
      float bp = __shfl_xor(bm, 2);
      float cp = __shfl_xor(cm, 2);
      float bo = is_im ? (bp*sa + bm*ca) : (bm*ca - bp*sa);
      float co = is_im ? (cp*sa + cm*ca) : (cm*ca - cp*sa);
      Br[((size_t)l*4+g)*64 + idx] = f2bf(bo);
      Cr[((size_t)l*4+g)*64 + idx] = f2bf(co);
    }
  }
}

// ------- K6Y (MFMA): y_diag per (chunk, group, t-quarter, head); q==3 also emits h_final --------
// R9: kc loop reduced q+2 -> q+1 trips (avg 3.5->2.5). The dropped last iteration only carried
// the superdiagonal column jj=(q+1)*32 for rows 62,63 (T=q*32+31) -> replaced by a cheap fp32
// fixup (4 shared length-32 dots on the owning quarter-wave). For q==3, the jj=128 column of
// h_final is a rank-1 update xup[l0+127] (x) Br[l0+127] -> fp32 fixup, ~16 MACs/lane.
// NOTE R3: q-merged variant (1 block/CU) regressed 191->306us — keep 1024-block structure.
__global__ void __launch_bounds__(256) k6y(
  const bf16* __restrict__ Br, const bf16* __restrict__ Cr, const bf16* __restrict__ xup,
  const float* __restrict__ dtb, const float* __restrict__ lamb, const float* __restrict__ A_log,
  bf16* __restrict__ ypr, bf16* __restrict__ hfin, float* __restrict__ dcb, float* __restrict__ csb)
{
  __shared__ __align__(16) bf16 Cs[64*40];
  __shared__ __align__(16) bf16 Bs[64*40];
  __shared__ __align__(16) bf16 Bsn[32*72];
  __shared__ __align__(16) bf16 Fs[64*72];
  __shared__ __align__(16) bf16 Xs[64*72];
  __shared__ float dt_l[128], lam_l[128], cs_l[128];
  __shared__ float u1s[160], u12s[160], vs_[32];
  int bx = blockIdx.x; int g = bx & 3, q = bx >> 2;
  int c = blockIdx.y;
  int h4 = blockIdx.z;
  int h = g*4 + h4;
  int tid = threadIdx.x;
  int l0 = c*TCH;
  int w = tid>>6, lane = tid&63, lm = lane&15, lq = lane>>4;
  float Ah = -__expf(A_log[g]);
  float dt_prev = (c>0) ? dtb[(l0-1)*4+g] : 0.f;
  if (tid<128){ dt_l[tid] = dtb[(l0+tid)*4+g]; lam_l[tid] = lamb[(l0+tid)*4+g]; }
  __syncthreads();
  if (tid < 64){
    float a = dt_l[2*tid]*Ah, b = dt_l[2*tid+1]*Ah;
    float s = a + b;
    #pragma unroll
    for (int off=1; off<64; off<<=1){
      float v = __shfl_up(s, off);
      if (tid >= off) s += v;
    }
    cs_l[2*tid+1] = s;
    cs_l[2*tid]   = s - b;
  }
  __syncthreads();
  float ref = cs_l[q*32+16];
  if (tid < 160){
    int jj = tid;
    float u1v = 0.f, u2v = 0.f;
    if (jj>=1 && jj<=128) u1v = lam_l[jj-1]*dt_l[jj-1]*__expf(fminf(ref-cs_l[jj-1],60.f));
    if (jj<=127){ float dtx = (jj>=1)? dt_l[jj-1] : dt_prev; u2v = (1.f-lam_l[jj])*dtx*__expf(fminf(ref-cs_l[jj],60.f)); }
    u1s[jj] = u1v; u12s[jj] = u1v+u2v;
  }
  if (tid < 32) vs_[tid] = __expf(fminf(cs_l[q*32+tid]-ref,60.f));
  // Cs staging: 1 unit/thread = (1 tl x 8 s): bf8s load + 4 packed b32 writes
  {
    int tl = tid & 31, s8 = (tid >> 5)*8;
    bf8s v = *(const bf8s*)&Cr[((size_t)(l0+q*32+tl)*4+g)*64 + s8];
    int cb = s8>>1;
    *(unsigned*)&Cs[((tl<<1)|0)*40 + cb]   = (unsigned)v.u[0] | ((unsigned)v.u[2]<<16);
    *(unsigned*)&Cs[((tl<<1)|1)*40 + cb]   = (unsigned)v.u[1] | ((unsigned)v.u[3]<<16);
    *(unsigned*)&Cs[((tl<<1)|0)*40 + cb+2] = (unsigned)v.u[4] | ((unsigned)v.u[6]<<16);
    *(unsigned*)&Cs[((tl<<1)|1)*40 + cb+2] = (unsigned)v.u[5] | ((unsigned)v.u[7]<<16);
  }
  __syncthreads();   // covers u1s/u12s/vs_ and Cs before use
  float vfin = __expf(fminf(cs_l[127]-ref,60.f));
  fv4 acc[4] = {};
  fv4 acch[2] = {};
  int nch = q+1;    // R9: last trip replaced by superdiagonal fixup below
  for (int kc=0; kc<nch; kc++){
    // Bs staging: 1 unit/thread = (1 jj x 8 s)
    {
      int jjloc = tid & 31, s8 = (tid >> 5)*8;
      int jj = kc*32 + jjloc; int l = l0-1+jj;
      bf8s v = {};
      if (l >= 0) v = *(const bf8s*)&Br[((size_t)l*4+g)*64 + s8];
      int cb = s8>>1;
      *(unsigned*)&Bs[(jjloc)*40    + cb]   = (unsigned)v.u[0] | ((unsigned)v.u[2]<<16);
      *(unsigned*)&Bs[(32+jjloc)*40 + cb]   = (unsigned)v.u[1] | ((unsigned)v.u[3]<<16);
      *(unsigned*)&Bs[(jjloc)*40    + cb+2] = (unsigned)v.u[4] | ((unsigned)v.u[6]<<16);
      *(unsigned*)&Bs[(32+jjloc)*40 + cb+2] = (unsigned)v.u[5] | ((unsigned)v.u[7]<<16);
    }
    // Bsn staging (q==3): 1 unit/thread = (2 jj x 4 s)
    if (q == 3){
      int jj0 = (tid & 15)*2, s4 = (tid >> 4)*4;
      int jj = kc*32 + jj0;
      int lA = l0-1+jj;
      ushort4 b0 = {0,0,0,0}, b1 = {0,0,0,0};
      if (lA >= 0) b0 = *(const ushort4*)&Br[((size_t)lA*4+g)*64 + s4];
      b1 = *(const ushort4*)&Br[((size_t)(lA+1)*4+g)*64 + s4];
      float g0 = vfin * u12s[jj], g1 = vfin * u12s[jj+1];
      unsigned short e0[4] = {b0.x,b0.y,b0.z,b0.w};
      unsigned short e1[4] = {b1.x,b1.y,b1.z,b1.w};
      #pragma unroll
      for (int i=0;i<4;i++){
        int s = s4+i;
        unsigned pk = (unsigned)f2bfu(g0*blo(e0[i])) | ((unsigned)f2bfu(g1*blo(e1[i]))<<16);
        *(unsigned*)&Bsn[(s>>1)*72 + (s&1)*32 + jj0] = pk;
      }
    }
    // Xs staging: 1 unit/thread = (2 jj x 8 p)
    {
      int jj0 = (tid & 15)*2, p8 = (tid >> 4)*8;
      int jj = kc*32 + jj0;
      int lA = l0-1+jj;
      bf8s v0 = {}, v1;
      if (lA >= 0) v0 = *(const bf8s*)&xup[((size_t)lA*16 + h)*128 + p8];
      v1 = *(const bf8s*)&xup[((size_t)(lA+1)*16 + h)*128 + p8];
      #pragma unroll
      for (int i=0;i<8;i++){
        int p = p8+i;
        *(unsigned*)&Xs[(p>>1)*72 + (p&1)*32 + jj0] = (unsigned)v0.u[i] | ((unsigned)v1.u[i]<<16);
      }
    }
    __syncthreads();
    {
      bfv8 a = *(const bfv8*)&Cs[(w*16+lm)*40 + lq*8];
      fv4 zz = {0.f,0.f,0.f,0.f};
      int rb = w*16 + lq*4;
      float vA = vs_[rb>>1];
      float vB = vs_[(rb>>1)+1];
      #pragma unroll
      for (int nt=0;nt<4;nt++){
        bfv8 b = *(const bfv8*)&Bs[(nt*16+lm)*40 + lq*8];
        fv4 s = __builtin_amdgcn_mfma_f32_16x16x32_bf16(a, b, zz, 0,0,0);
        int col = nt*16+lm;
        int jj = kc*32 + (col&31);
        float u1v = u1s[jj], u12v = u12s[jj];
        #pragma unroll
        for (int r=0;r<4;r++){
          int row = rb + r;
          float vT = (r<2) ? vA : vB;
          float cf;
          if (kc < q) cf = u12v;
          else {
            int T = q*32 + (row>>1);
            cf = (jj<=T) ? u12v : ((jj==T+1) ? u1v : 0.f);
          }
          Fs[row*72+col] = f2bf(cf*vT*s[r]);
        }
      }
    }
    // Fs is wave-private (writer rows == reader rows per wave): wave-local wait, no barrier
    asm volatile("s_waitcnt lgkmcnt(0)" ::: "memory");
    __builtin_amdgcn_sched_barrier(0);
    #pragma unroll
    for (int r2=0;r2<2;r2++){
      bfv8 a = *(const bfv8*)&Fs[(w*16+lm)*72 + r2*32 + lq*8];
      #pragma unroll
      for (int nt=0;nt<4;nt++){
        bfv8 b = *(const bfv8*)&Xs[(nt*16+lm)*72 + r2*32 + lq*8];
        acc[nt] = __builtin_amdgcn_mfma_f32_16x16x32_bf16(a, b, acc[nt], 0,0,0);
      }
    }
    if (q == 3){
      #pragma unroll
      for (int r2=0;r2<2;r2++){
        bfv8 a = *(const bfv8*)&Xs[(w*16+lm)*72 + r2*32 + lq*8];
        #pragma unroll
        for (int nt2=0;nt2<2;nt2++){
          bfv8 b = *(const bfv8*)&Bsn[(nt2*16+lm)*72 + r2*32 + lq*8];
          acch[nt2] = __builtin_amdgcn_mfma_f32_16x16x32_bf16(a, b, acch[nt2], 0,0,0);
        }
      }
    }
    __syncthreads();
  }
  // R9 fixup 1 (all q): superdiagonal jj=(q+1)*32 contributes only to rows 62,63 (T=q*32+31).
  // s(row,(rB,jj*)) = dot_n(Cs[row], Br[l0+T31][n*2+rB]); acc += vT*u1[jj*]*s*xup[l0+T31][pp*2+rB]
  {
    int lstar = l0 + q*32 + 31;
    if (w == 3 && lq == 3){
      int n0 = lm*2;
      float4 bv = ldb4(&Br[((size_t)lstar*4+g)*64 + n0*2]);
      float c62a = bf2f(Cs[62*40+n0]), c62b = bf2f(Cs[62*40+n0+1]);
      float c63a = bf2f(Cs[63*40+n0]), c63b = bf2f(Cs[63*40+n0+1]);
      float s620 = c62a*bv.x + c62b*bv.z;
      float s621 = c62a*bv.y + c62b*bv.w;
      float s630 = c63a*bv.x + c63b*bv.z;
      float s631 = c63a*bv.y + c63b*bv.w;
      #pragma unroll
      for (int off=1; off<16; off<<=1){
        s620 += __shfl_xor(s620, off);
        s621 += __shfl_xor(s621, off);
        s630 += __shfl_xor(s630, off);
        s631 += __shfl_xor(s631, off);
      }
      float cf = u1s[(q+1)*32] * vs_[31];
      #pragma unroll
      for (int nt=0; nt<4; nt++){
        int pp = nt*16+lm;
        ushort2 xv = *(const ushort2*)&xup[((size_t)lstar*16+h)*128 + pp*2];
        float x0 = blo((unsigned)xv.x), x1 = blo((unsigned)xv.y);
        acc[nt][2] += cf*(s620*x0 + s621*x1);
        acc[nt][3] += cf*(s630*x0 + s631*x1);
      }
    }
  }
  // R9 fixup 2 (q==3): h_final jj=128 rank-1 update: acch(pp,n) += gcv*xup[l0+127][pp*2+rB]*Br[l0+127][n*2+rB]
  if (q == 3){
    int l127 = l0 + 127;
    float gcv = vfin * u12s[128];
    float xr[4][2];
    {
      bf8s xv = *(const bf8s*)&xup[((size_t)l127*16+h)*128 + (w*16+lq*4)*2];
      #pragma unroll
      for (int r=0;r<4;r++){ xr[r][0] = blo((unsigned)xv.u[r*2]); xr[r][1] = blo((unsigned)xv.u[r*2+1]); }
    }
    #pragma unroll
    for (int nt2=0; nt2<2; nt2++){
      ushort2 bv = *(const ushort2*)&Br[((size_t)l127*4+g)*64 + (nt2*16+lm)*2];
      float b0 = blo((unsigned)bv.x), b1 = blo((unsigned)bv.y);
      #pragma unroll
      for (int r=0;r<4;r++)
        acch[nt2][r] += gcv*(xr[r][0]*b0 + xr[r][1]*b1);
    }
  }
  #pragma unroll
  for (int nt=0;nt<4;nt++){
    int p = nt*16+lm;
    #pragma unroll
    for (int r=0;r<4;r++){
      int row = w*16+lq*4+r;
      int T = q*32+(row>>1), r1 = row&1;
      ypr[((size_t)(l0+T)*16 + h)*128 + p*2+r1] = f2bf(acc[nt][r]);
    }
  }
  if (q == 3){
    #pragma unroll
    for (int nt2=0;nt2<2;nt2++){
      int n = nt2*16+lm;
      #pragma unroll
      for (int r=0;r<4;r++){
        int p = w*16+lq*4+r;
        hfin[(((size_t)c*16+h)*64 + p)*32 + n] = f2bf(acch[nt2][r]);
      }
    }
    if (tid == 0) dcb[c*16+h] = __expf(cs_l[127]);
  }
  if (q == 0 && h4 == 0 && tid < 128) csb[(c*4+g)*128 + tid] = cs_l[tid];
}

// ------- K8AF: fused inter-chunk scan + y_off (MFMA) + ydown (MFMA) + gates, per (c,h) ---------
__global__ void __launch_bounds__(256) k8af(
  const bf16* __restrict__ Cr, const bf16* __restrict__ hfin,
  const float* __restrict__ dcb, const float* __restrict__ csb,
  bf16* __restrict__ ypr, const bf16* __restrict__ WydT,
  const bf16* __restrict__ proj, const float* __restrict__ Dp)
{
  __shared__ __align__(16) char arena[57856];
  bf16* hT   = (bf16*)(arena + 34816);   // [64*40]  5120 B shared
  float* cse = (float*)(arena + 39936);  // [128]     512 B shared
  bf16* Wds  = (bf16*)(arena + 40448);   // [64*136] 17408 B shared
  int h = blockIdx.x, c = blockIdx.y;
  int g = h >> 2;
  int tid = threadIdx.x;
  int l0 = c*TCH;
  int w = tid>>6, lane = tid&63, lm = lane&15, lq = lane>>4;
  for (int u4 = tid; u4 < 1024; u4 += 256){
    int tl = u4>>3, s8 = (u4&7)*8;
    bf8s v = *(const bf8s*)&Cr[((size_t)(l0+tl)*4+g)*64 + s8];
    int cb = s8>>1;
    bf16* Cw = (bf16*)(arena + (tl>>5)*8704);
    int r0l = (tl<<1)&63;
    *(unsigned*)&Cw[(r0l  )*40 + cb]   = (unsigned)v.u[0] | ((unsigned)v.u[2]<<16);
    *(unsigned*)&Cw[(r0l|1)*40 + cb]   = (unsigned)v.u[1] | ((unsigned)v.u[3]<<16);
    *(unsigned*)&Cw[(r0l  )*40 + cb+2] = (unsigned)v.u[4] | ((unsigned)v.u[6]<<16);
    *(unsigned*)&Cw[(r0l|1)*40 + cb+2] = (unsigned)v.u[5] | ((unsigned)v.u[7]<<16);
  }
  for (int e = tid; e < 1024; e += 256){
    int qq = e>>4, k8 = (e&15)*8;
    *(bf8s*)&Wds[qq*136 + k8] = *(const bf8s*)&WydT[qq*128 + k8];
  }
  {
    int e0 = tid*8;
    float carry[8] = {};
    for (int j = 0; j < c; j++){
      float dc = dcb[j*16+h];
      float4 a = ldb4(&hfin[((size_t)j*16+h)*2048 + e0]);
      float4 b = ldb4(&hfin[((size_t)j*16+h)*2048 + e0 + 4]);
      carry[0]=carry[0]*dc+a.x; carry[1]=carry[1]*dc+a.y; carry[2]=carry[2]*dc+a.z; carry[3]=carry[3]*dc+a.w;
      carry[4]=carry[4]*dc+b.x; carry[5]=carry[5]*dc+b.y; carry[6]=carry[6]*dc+b.z; carry[7]=carry[7]*dc+b.w;
    }
    int p = e0>>5, n = e0&31;
    stb4(&hT[p*40+n],   make_float4(carry[0],carry[1],carry[2],carry[3]));
    stb4(&hT[p*40+n+4], make_float4(carry[4],carry[5],carry[6],carry[7]));
  }
  if (tid < 128) cse[tid] = __expf(csb[(c*4+g)*128 + tid]);
  __syncthreads();   // the ONLY barrier: C2s/hT/cse/Wds staged cooperatively
  bf16* C2w = (bf16*)(arena + w*8704);
  bf16* Yfw = (bf16*)(arena + w*8704);
  float yfull[4][4][4];
  fv4 zz = {0.f,0.f,0.f,0.f};
  #pragma unroll
  for (int mi=0;mi<4;mi++){
    bfv8 a = *(const bfv8*)&C2w[(mi*16+lm)*40 + lq*8];
    #pragma unroll
    for (int nt=0;nt<4;nt++){
      bfv8 b = *(const bfv8*)&hT[(nt*16+lm)*40 + lq*8];
      fv4 s = __builtin_amdgcn_mfma_f32_16x16x32_bf16(a, b, zz, 0,0,0);
      int p = nt*16+lm;
      #pragma unroll
      for (int r=0;r<4;r++){
        int row = (w*4+mi)*16+lq*4+r;
        int tl = row>>1, r1 = row&1;
        float yd = bf2f(ypr[((size_t)(l0+tl)*16 + h)*128 + p*2 + r1]);
        yfull[mi][nt][r] = yd + cse[tl]*s[r];
      }
    }
  }
  asm volatile("" ::: "memory");  // compile fence: keep C2s reads above Yf writes (alias)
  #pragma unroll
  for (int mi=0;mi<4;mi++){
    #pragma unroll
    for (int nt=0;nt<4;nt++){
      int p = nt*16+lm;
      #pragma unroll
      for (int r=0;r<4;r++){
        int row = (w*4+mi)*16+lq*4+r;
        int tl = row>>1, r1 = row&1;
        Yfw[(tl&31)*136 + p*2 + r1] = f2bf(yfull[mi][nt][r]);
      }
    }
  }
  // Yf is wave-private: wave-local wait, no barrier
  asm volatile("s_waitcnt lgkmcnt(0)" ::: "memory");
  __builtin_amdgcn_sched_barrier(0);
  fv4 acc2[2][4] = {};
  #pragma unroll
  for (int kq=0;kq<4;kq++){
    #pragma unroll
    for (int m2=0;m2<2;m2++){
      bfv8 a = *(const bfv8*)&Yfw[(m2*16+lm)*136 + kq*32 + lq*8];
      #pragma unroll
      for (int nt2=0;nt2<4;nt2++){
        bfv8 b = *(const bfv8*)&Wds[(nt2*16+lm)*136 + kq*32 + lq*8];
        acc2[m2][nt2] = __builtin_amdgcn_mfma_f32_16x16x32_bf16(a, b, acc2[m2][nt2], 0,0,0);
      }
    }
  }
  float dv = Dp[h];
  #pragma unroll
  for (int m2=0;m2<2;m2++){
    #pragma unroll
    for (int nt2=0;nt2<4;nt2++){
      int qq = nt2*16+lm;
      #pragma unroll
      for (int r=0;r<4;r++){
        int tl = (w*2+m2)*16 + lq*4 + r;
        size_t lrow = (size_t)(l0+tl)*DPROJ;
        float x = bf2f(proj[lrow + 1024 + h*64 + qq]);
        float z = bf2f(proj[lrow + h*64 + qq]);
        float xs = x/(1.f+__expf(-x));
        float zs = z/(1.f+__expf(-z));
        float outv = (acc2[m2][nt2][r] + dv*xs)*zs;
        ypr[((size_t)(l0+tl)*16 + h)*128 + 64 + qq] = f2bf(outv);
      }
    }
  }
}

extern "C" void kernel_launch(void* const* d_in, const int* in_sizes, int n_in,
                              void* d_out, int out_size, void* d_ws, size_t ws_size,
                              hipStream_t stream) {
  const float* u       = (const float*)d_in[0];
  const float* W_in    = (const float*)d_in[1];
  const float* b_in    = (const float*)d_in[2];
  const float* W_xup   = (const float*)d_in[3];
  const float* W_ydown = (const float*)d_in[4];
  const float* A_log   = (const float*)d_in[5];
  const float* theta_l = (const float*)d_in[6];
  const float* D_p     = (const float*)d_in[7];
  const float* wB      = (const float*)d_in[8];
  const float* wC      = (const float*)d_in[9];
  const float* biasB   = (const float*)d_in[10];
  const float* biasC   = (const float*)d_in[11];
  const float* W_out   = (const float*)d_in[12];
  float* out = (float*)d_out;

  char* w = (char*)d_ws;
  bf16*  proj  = (bf16*)(w);                       // 10,518,528 B
  float* dlraw = (float*)(w + 10518528);           //     65,536 B
  float* dtb   = (float*)(w + 10584064);           //     32,768 B
  float* lamb  = (float*)(w + 10616832);           //     32,768 B
  float* csdt  = (float*)(w + 10649600);           //     32,768 B
  bf16*  Brb   = (bf16*)(w + 10682368);            //  1,048,576 B
  bf16*  Crb   = (bf16*)(w + 11730944);            //  1,048,576 B
  bf16*  xupb  = (bf16*)(w + 12779520);            //  8,388,608 B
  bf16*  hfin  = (bf16*)(w + 21168128);            //  1,048,576 B
  bf16*  WxupT = (bf16*)(w + 22216704);            //     16,384 B (slack after hfin)
  float* dcb   = (float*)(w + 23265280);           //      1,024 B
  float* csb   = (float*)(w + 23266304);           //     32,768 B
  bf16*  ypr   = (bf16*)(w + 23299072);            //  8,388,608 B
  bf16*  WinT  = (bf16*)(w + 23299072);            //  aliased over ypr (dead once k6y writes ypr)
  bf16*  ubf   = (bf16*)(w + 31687680);            //  2,097,152 B
  bf16*  WoutT = (bf16*)(w + 33784832);            //  1,048,576 B
  bf16*  WydT  = (bf16*)(w + 34833408);            //     16,384 B

  prep<<<2896,256,0,stream>>>(u, ubf, W_in, WinT, W_out, WoutT, W_ydown, WydT, W_xup, WxupT);
  gemm1_mfma<<<dim3(21,16),256,0,stream>>>(ubf, WinT, b_in, proj, dlraw);
  k23<<<1,1024,0,stream>>>(dlraw, dtb, lamb, csdt);
  k45x<<<512,256,0,stream>>>(proj, WxupT, xupb, wB, wC, biasB, biasC, theta_l, csdt, Brb, Crb);
  k6y<<<dim3(16,16,4),256,0,stream>>>(Brb, Crb, xupb, dtb, lamb, A_log, ypr, hfin, dcb, csb);
  k8af<<<dim3(16,16),256,0,stream>>>(Crb, hfin, dcb, csb, ypr, WydT, proj, D_p);
  gemmo_mfma<<<dim3(8,32),256,0,stream>>>(ypr, WoutT, out);
}